// Round 6
// baseline (412.511 us; speedup 1.0000x reference)
//
#include <hip/hip_runtime.h>
#include <hip/hip_fp16.h>
#include <math.h>

// SS2D fused block. B=2, H=W=64, L=4096, C=96, Di=192, K=4, N=16, R=6.
// Input dtype (bf16 vs f32) detected at runtime; internal compute f32 (dt/z/ys f16).
// Workspace: ~52 MB.

static constexpr int Bsz = 2;
static constexpr int Lc  = 4096;
static constexpr int Cc  = 96;
static constexpr int Dd  = 192;
static constexpr int Kk  = 4;
static constexpr int NC  = 32;     // chunks of 128 steps

__device__ __forceinline__ float bu(unsigned short v) {
    return __uint_as_float((unsigned int)v << 16);
}
__device__ __forceinline__ unsigned short f2b(float f) {
    unsigned int u = __float_as_uint(f);
    return (unsigned short)((u + 0x7fffu + ((u >> 16) & 1u)) >> 16);
}

// DPP 16-lane row reduction: 4 full-rate VALU adds, no DS pipe.
template<int CTRL>
__device__ __forceinline__ float dppadd(float x) {
    return x + __int_as_float(__builtin_amdgcn_update_dpp(
        0, __float_as_int(x), CTRL, 0xf, 0xf, true));
}
__device__ __forceinline__ float red16(float x) {
    x = dppadd<0xB1>(x);    // quad_perm [1,0,3,2]  (xor 1)
    x = dppadd<0x4E>(x);    // quad_perm [2,3,0,1]  (xor 2)
    x = dppadd<0x124>(x);   // row_ror:4
    x = dppadd<0x128>(x);   // row_ror:8
    return x;
}

// ---------------- K0: dtype detector (bf16 vs f32) ----------------
__global__ __launch_bounds__(256) void k0_detect(const unsigned short* __restrict__ x,
                                                 int* __restrict__ flag)
{
    __shared__ int s[256];
    int cnt = 0;
    for (int i = threadIdx.x; i < 4096; i += 256) {
        int e = (x[i] >> 7) & 0xFF;
        cnt += (e >= 118 && e <= 131) ? 1 : 0;
    }
    s[threadIdx.x] = cnt;
    __syncthreads();
    for (int st = 128; st > 0; st >>= 1) {
        if (threadIdx.x < st) s[threadIdx.x] += s[threadIdx.x + st];
        __syncthreads();
    }
    if (threadIdx.x == 0) flag[0] = (s[0] >= 3072) ? 1 : 0;
}

// ---------------- K0b: convert weight inputs (1..11) to canonical f32 ----------------
struct Cv {
    const void* src[11];
    int off[11];
    int n[11];
};
__global__ __launch_bounds__(256) void k0b_convert(Cv cv, const int* __restrict__ flag,
                                                   float* __restrict__ dstbase)
{
    int bf = flag[0];
    int t = blockIdx.y;
    int i = blockIdx.x * 256 + threadIdx.x;
    if (i >= cv.n[t]) return;
    float v;
    if (bf) v = bu(((const unsigned short*)cv.src[t])[i]);
    else    v = ((const float*)cv.src[t])[i];
    dstbase[cv.off[t] + i] = v;
}

// ---------------- K1: in_proj GEMM (8192x384x96), split xi / silu(z) ----------------
__global__ __launch_bounds__(256) void k1_inproj(const void* __restrict__ xraw,
                                                 const int* __restrict__ flag,
                                                 const float* __restrict__ wf,
                                                 float* __restrict__ xi, __half* __restrict__ zs)
{
    __shared__ float xT[32 * 97];
    __shared__ float wT[96 * 97];
    const int bf = flag[0];
    int tile = blockIdx.x >> 2, jq = blockIdx.x & 3;
    int b = tile >> 7;
    int l0 = (tile & 127) << 5;
    int j0 = jq * 96;
    for (int e = threadIdx.x; e < 32 * 96; e += 256) {
        int i = e / 96, c = e % 96;
        size_t idx = (size_t)(b * Lc + l0 + i) * Cc + c;
        xT[i * 97 + c] = bf ? bu(((const unsigned short*)xraw)[idx])
                            : ((const float*)xraw)[idx];
    }
    for (int e = threadIdx.x; e < 96 * 96; e += 256) {
        int j = e / 96, c = e % 96;
        wT[j * 97 + c] = wf[(size_t)(j0 + j) * Cc + c];
    }
    __syncthreads();
    int jj = threadIdx.x & 31, ll = threadIdx.x >> 5;
    float acc[4][3];
#pragma unroll
    for (int i = 0; i < 4; i++)
#pragma unroll
        for (int m = 0; m < 3; m++) acc[i][m] = 0.f;
    for (int c = 0; c < 96; ++c) {
        float xv[4], wv[3];
#pragma unroll
        for (int i = 0; i < 4; i++) xv[i] = xT[(ll * 4 + i) * 97 + c];
#pragma unroll
        for (int m = 0; m < 3; m++) wv[m] = wT[(jj + 32 * m) * 97 + c];
#pragma unroll
        for (int i = 0; i < 4; i++)
#pragma unroll
            for (int m = 0; m < 3; m++) acc[i][m] += xv[i] * wv[m];
    }
#pragma unroll
    for (int i = 0; i < 4; i++) {
        int l = l0 + ll * 4 + i;
#pragma unroll
        for (int m = 0; m < 3; m++) {
            int j = j0 + jj + 32 * m;
            float v = acc[i][m];
            if (j < Dd) xi[(size_t)(b * Lc + l) * Dd + j] = v;
            else        zs[(size_t)(b * Lc + l) * Dd + (j - Dd)] = __float2half(v / (1.f + __expf(-v)));
        }
    }
}

// ---------------- K2a: transpose xi (B,L,Di) -> xiT (B,Di,L) ----------------
__global__ __launch_bounds__(256) void k2a_transpose(const float* __restrict__ xi,
                                                     float* __restrict__ xiT)
{
    __shared__ float t[64 * 65];
    int bid = blockIdx.x;
    int lq = bid & 63, dq = (bid >> 6) % 3, b = bid / 192;
    int l0 = lq * 64, d0 = dq * 64;
    for (int e = threadIdx.x; e < 4096; e += 256) {
        int i = e >> 6, j = e & 63;
        t[i * 65 + j] = xi[(size_t)(b * Lc + l0 + i) * Dd + d0 + j];
    }
    __syncthreads();
    for (int e = threadIdx.x; e < 4096; e += 256) {
        int j = e >> 6, i = e & 63;
        xiT[(size_t)(b * Dd + d0 + j) * Lc + l0 + i] = t[i * 65 + j];
    }
}

// -------- K2b: depthwise 3x3 conv + bias + SiLU (channel-first), writes xc and uT --------
__global__ __launch_bounds__(256) void k2b_conv(const float* __restrict__ xiT,
                                                const float* __restrict__ cwf,
                                                const float* __restrict__ cbf,
                                                float* __restrict__ xc,
                                                float* __restrict__ uT)
{
    __shared__ float inl[34 * 66];   // rows h0-1..h0+32, cols zero-padded
    __shared__ float outl[32 * 65];
    int bid = blockIdx.x;
    int half = bid & 1;
    int d = (bid >> 1) % Dd;
    int b = bid / (2 * Dd);
    int h0 = half * 32;
    const float* src = xiT + (size_t)(b * Dd + d) * Lc;
    for (int r = threadIdx.x; r < 34; r += 256) {
        inl[r * 66 + 0] = 0.f;
        inl[r * 66 + 65] = 0.f;
    }
    for (int e = threadIdx.x; e < 34 * 64; e += 256) {
        int row = e >> 6, w = e & 63;
        int h = h0 - 1 + row;
        inl[row * 66 + 1 + w] = (h >= 0 && h < 64) ? src[h * 64 + w] : 0.f;
    }
    __syncthreads();
    float wgt[9];
#pragma unroll
    for (int t = 0; t < 9; t++) wgt[t] = cwf[d * 9 + t];
    float bias = cbf[d];
    int hs = threadIdx.x >> 6, w = threadIdx.x & 63;
    float* dstrow = xc + (size_t)(b * Dd + d) * Lc;
#pragma unroll
    for (int it = 0; it < 8; ++it) {
        int hh = it * 4 + hs;
        float acc = bias;
#pragma unroll
        for (int dy = 0; dy < 3; ++dy) {
            const float* rp = &inl[(hh + dy) * 66 + w];
#pragma unroll
            for (int dx = 0; dx < 3; ++dx)
                acc += rp[dx] * wgt[dy * 3 + dx];
        }
        float s = acc / (1.f + __expf(-acc));
        dstrow[(h0 + hh) * 64 + w] = s;
        outl[hh * 65 + w] = s;
    }
    __syncthreads();
    float* udst = uT + (size_t)(b * Dd + d) * Lc;
    for (int e = threadIdx.x; e < 2048; e += 256) {
        int w2 = e >> 5, hh2 = e & 31;
        udst[w2 * 64 + h0 + hh2] = outl[hh2 * 65 + w2];
    }
}

// -------- K3: per-direction projection (38 outs) + dt-proj + softplus --------
__global__ __launch_bounds__(256) void k3_proj(const float* __restrict__ xc,
                                               const float* __restrict__ xpwf,
                                               const float* __restrict__ dtwf,
                                               const float* __restrict__ dtbf,
                                               __half* __restrict__ dtH,
                                               float* __restrict__ BsT, float* __restrict__ CsT)
{
    __shared__ float Wl[192 * 40];
    __shared__ float dtWl[192 * 8];
    __shared__ float biasl[192];
    __shared__ float rawq[4][64 * 41];
    int bid = blockIdx.x;
    int pt = bid & 63, k = (bid >> 6) & 3, b = bid >> 8;
    bool colm = (k & 1);
    int s0 = pt * 64;
    for (int e = threadIdx.x; e < 38 * 192; e += 256) {
        int cp = e / 192, d = e % 192;
        Wl[d * 40 + cp] = xpwf[(size_t)(k * 38 + cp) * 192 + d];
    }
    for (int e = threadIdx.x; e < 2 * 192; e += 256) {
        Wl[(e >> 1) * 40 + 38 + (e & 1)] = 0.f;
    }
    for (int e = threadIdx.x; e < 192 * 6; e += 256) {
        int d = e / 6, r = e % 6;
        dtWl[d * 8 + r] = dtwf[(size_t)(k * 192 + d) * 6 + r];
    }
    for (int e = threadIdx.x; e < 192; e += 256) biasl[e] = dtbf[k * 192 + e];
    __syncthreads();
    int pi = threadIdx.x & 63, q = threadIdx.x >> 6;
    int pos = colm ? (pi * 64 + pt) : (pt * 64 + pi);
    float acc[40];
#pragma unroll
    for (int i = 0; i < 40; i++) acc[i] = 0.f;
    const float* xrow = xc + (size_t)b * Dd * Lc + pos;
    for (int dd = 0; dd < 48; ++dd) {
        int d = q * 48 + dd;
        float xv = xrow[(size_t)d * Lc];
#pragma unroll
        for (int c4 = 0; c4 < 10; ++c4) {
            float4 w4 = *reinterpret_cast<const float4*>(&Wl[d * 40 + c4 * 4]);
            acc[c4 * 4 + 0] += w4.x * xv; acc[c4 * 4 + 1] += w4.y * xv;
            acc[c4 * 4 + 2] += w4.z * xv; acc[c4 * 4 + 3] += w4.w * xv;
        }
    }
    float* myraw = &rawq[q][pi * 41];
#pragma unroll
    for (int i = 0; i < 40; i++) myraw[i] = acc[i];
    __syncthreads();
    for (int e = threadIdx.x; e < 64 * 40; e += 256) {
        int p = e / 40, cp = e % 40;
        rawq[0][p * 41 + cp] = rawq[0][p * 41 + cp] + rawq[1][p * 41 + cp]
                             + rawq[2][p * 41 + cp] + rawq[3][p * 41 + cp];
    }
    __syncthreads();
    // B/C transposed: [ (b,k) ][ n ][ t ]  (f32)
    for (int e = threadIdx.x; e < 64 * 16; e += 256) {
        int n = e >> 6, p = e & 63;
        size_t base = ((size_t)((b * Kk + k) * 16 + n)) * Lc + s0 + p;
        BsT[base] = rawq[0][p * 41 + 6 + n];
        CsT[base] = rawq[0][p * 41 + 22 + n];
    }
    for (int dd = 0; dd < 48; ++dd) {
        int d = q * 48 + dd;
        float s = biasl[d];
#pragma unroll
        for (int r = 0; r < 6; r++) s += rawq[0][pi * 41 + r] * dtWl[d * 8 + r];
        float sp = fmaxf(s, 0.f) + log1pf(__expf(-fabsf(s)));
        dtH[((size_t)(b * Kk + k) * Dd + d) * Lc + s0 + pi] = __float2half(sp);
    }
}

// ---------------- KSCAN: chunked selective scan, software-pipelined ----------------
// 8-step sub-iterations, double-buffered loads, DPP reduction, merged fwd/rev grid.
template<int REV, int PASS3>
__device__ __forceinline__ void scan_body(const __half* __restrict__ dtp,
                                          const float* __restrict__ up,
                                          const float* __restrict__ Bn,
                                          const float* __restrict__ Cn,
                                          float An, float Dsv, int c, int n,
                                          float* __restrict__ P, float* __restrict__ S,
                                          size_t pidx, __half* __restrict__ yrow)
{
    float h = PASS3 ? P[pidx] : 0.f;
    float sdt = 0.f, ystash = 0.f;
    const int t0 = c * 128;

#define MBASE(s) (REV ? (Lc - 8 - (t0 + (s) * 8)) : (t0 + (s) * 8))

    float4 uA[2], bA[2], cA[2]; uint4 dA;
    float4 uB[2], bB[2], cB[2]; uint4 dB;

#define LOADBUF(mb, uu, bb, cc, dd)                                            \
    {                                                                          \
        const float4* pu = reinterpret_cast<const float4*>(up + (mb));         \
        uu[0] = pu[0]; uu[1] = pu[1];                                          \
        const float4* pb = reinterpret_cast<const float4*>(Bn + (mb));         \
        bb[0] = pb[0]; bb[1] = pb[1];                                          \
        if (PASS3) {                                                           \
            const float4* pc = reinterpret_cast<const float4*>(Cn + (mb));     \
            cc[0] = pc[0]; cc[1] = pc[1];                                      \
        }                                                                      \
        dd = *reinterpret_cast<const uint4*>(dtp + (mb));                      \
    }

#define COMPBUF(s, uu, bb, cc, dd)                                             \
    {                                                                          \
        _Pragma("unroll")                                                      \
        for (int j = 0; j < 8; ++j) {                                          \
            const int jj = REV ? (7 - j) : j;                                  \
            __half2 hp = reinterpret_cast<const __half2*>(&dd)[jj >> 1];       \
            float dtv = (jj & 1) ? __high2float(hp) : __low2float(hp);         \
            float uv = reinterpret_cast<const float*>(uu)[jj];                 \
            float bv = reinterpret_cast<const float*>(bb)[jj];                 \
            float a = __expf(dtv * An);                                        \
            if (!PASS3) sdt += dtv;                                            \
            h = a * h + (dtv * uv) * bv;                                       \
            if (PASS3) {                                                       \
                float cv = reinterpret_cast<const float*>(cc)[jj];             \
                float yv = red16(h * cv);                                      \
                if ((((s) & 1) * 8 + j) == n) ystash = yv + uv * Dsv;          \
            }                                                                  \
        }                                                                      \
        if (PASS3 && ((s) & 1)) {                                              \
            int tb = t0 + ((s) & ~1) * 8 + n;                                  \
            int aw = REV ? (Lc - 1 - tb) : tb;                                 \
            yrow[aw] = __float2half(ystash);                                   \
        }                                                                      \
    }

    LOADBUF(MBASE(0), uA, bA, cA, dA);
#pragma unroll
    for (int it = 0; it < 8; ++it) {
        const int sA = 2 * it, sB = 2 * it + 1;
        LOADBUF(MBASE(sB), uB, bB, cB, dB);
        COMPBUF(sA, uA, bA, cA, dA);
        if (it < 7) LOADBUF(MBASE(sB + 1), uA, bA, cA, dA);
        COMPBUF(sB, uB, bB, cB, dB);
    }

    if (!PASS3) {
        P[pidx] = __expf(An * sdt);
        S[pidx] = h;
    }
#undef MBASE
#undef LOADBUF
#undef COMPBUF
}

template<int PASS3>
__global__ __launch_bounds__(256, 4) void kscan(const __half* __restrict__ dtH,
                                                const float* __restrict__ xc,
                                                const float* __restrict__ uT,
                                                const float* __restrict__ BsT,
                                                const float* __restrict__ CsT,
                                                const float* __restrict__ alogf,
                                                const float* __restrict__ dsf,
                                                float* __restrict__ P,
                                                float* __restrict__ S,
                                                __half* __restrict__ ysH)
{
    int c  = blockIdx.x & 31;
    int t1 = blockIdx.x >> 5;          // 0..95
    int dg = t1 % 12;
    int kk = (t1 / 12) & 3;
    int b  = t1 / 48;
    int n  = threadIdx.x & 15, dl = threadIdx.x >> 4;
    int d  = dg * 16 + dl;

    const __half* dtp = dtH + ((size_t)((b * Kk + kk) * Dd + d)) * Lc;
    const float*  up  = (kk & 1) ? uT + (size_t)(b * Dd + d) * Lc
                                 : xc + (size_t)(b * Dd + d) * Lc;
    const float*  Bn  = BsT + ((size_t)((b * Kk + kk) * 16 + n)) * Lc;
    const float*  Cn  = CsT + ((size_t)((b * Kk + kk) * 16 + n)) * Lc;
    float An  = -__expf(alogf[(kk * Dd + d) * 16 + n]);
    float Dsv = PASS3 ? dsf[kk * Dd + d] : 0.f;
    size_t pidx = (((size_t)(b * Kk + kk) * Dd + d) * NC + c) * 16 + n;
    __half* yrow = PASS3 ? ysH + ((size_t)(kk * Bsz + b) * Dd + d) * Lc : nullptr;

    if (kk >= 2) scan_body<1, PASS3>(dtp, up, Bn, Cn, An, Dsv, c, n, P, S, pidx, yrow);
    else         scan_body<0, PASS3>(dtp, up, Bn, Cn, An, Dsv, c, n, P, S, pidx, yrow);
}

// ---------------- K6: chunk-level scan; carry-in written in place over P ----------------
__global__ __launch_bounds__(256) void k6_pass2(float* __restrict__ P, const float* __restrict__ S)
{
    int g = blockIdx.x * 256 + threadIdx.x;   // 24576
    int n = g & 15;
    int chain = g >> 4;
    size_t base = (size_t)chain * NC * 16 + n;
    float h = 0.f;
    for (int c = 0; c < NC; ++c) {
        size_t id = base + (size_t)c * 16;
        float p = P[id], s = S[id];
        P[id] = h;
        h = p * h + s;
    }
}

// ---------------- K8t: ysT = transpose(ys1 + ys3) per (b,d) ----------------
__global__ __launch_bounds__(256) void k8t(const __half* __restrict__ ysH,
                                           __half* __restrict__ ysT)
{
    __shared__ float t[64 * 65];
    int bid = blockIdx.x;
    int d = bid % Dd, b = bid / Dd;
    const __half* y1 = ysH + ((size_t)(1 * Bsz + b) * Dd + d) * Lc;
    const __half* y3 = ysH + ((size_t)(3 * Bsz + b) * Dd + d) * Lc;
    __half* dst = ysT + ((size_t)b * Dd + d) * Lc;
    for (int e = threadIdx.x; e < 4096; e += 256)
        t[(e >> 6) * 65 + (e & 63)] = __half2float(y1[e]) + __half2float(y3[e]);
    __syncthreads();
    for (int e = threadIdx.x; e < 4096; e += 256)
        dst[e] = __float2half(t[(e & 63) * 65 + (e >> 6)]);
}

// ---------------- K8: merge + LayerNorm + SiLU(z) gate -> gH ----------------
__global__ __launch_bounds__(256) void k8_norm(const __half* __restrict__ ysH,
                                               const __half* __restrict__ ysT,
                                               const __half* __restrict__ zsH,
                                               const float* __restrict__ nwf,
                                               const float* __restrict__ nbf,
                                               __half* __restrict__ gH)
{
    __shared__ float yt[192 * 33];
    __shared__ float ps1[8 * 32], ps2[8 * 32];
    __shared__ float mu[32], rs[32];
    int bid = blockIdx.x;
    int pt = bid & 127, b = bid >> 7;
    int p0 = pt * 32;
    for (int e = threadIdx.x; e < 192 * 32; e += 256) {
        int d = e >> 5, p = e & 31;
        size_t r0 = ((size_t)(0 * Bsz + b) * Dd + d) * Lc + p0 + p;
        size_t r2 = ((size_t)(2 * Bsz + b) * Dd + d) * Lc + p0 + p;
        size_t rt = ((size_t)b * Dd + d) * Lc + p0 + p;
        yt[d * 33 + p] = __half2float(ysH[r0]) + __half2float(ysH[r2]) + __half2float(ysT[rt]);
    }
    __syncthreads();
    {
        int p = threadIdx.x & 31, q = threadIdx.x >> 5;
        float s1 = 0.f, s2 = 0.f;
        for (int dd = 0; dd < 24; ++dd) {
            float v = yt[(q * 24 + dd) * 33 + p];
            s1 += v; s2 += v * v;
        }
        ps1[q * 32 + p] = s1; ps2[q * 32 + p] = s2;
    }
    __syncthreads();
    if (threadIdx.x < 32) {
        int p = threadIdx.x;
        float s1 = 0.f, s2 = 0.f;
        for (int q = 0; q < 8; ++q) { s1 += ps1[q * 32 + p]; s2 += ps2[q * 32 + p]; }
        float m = s1 * (1.f / 192.f);
        float var = s2 * (1.f / 192.f) - m * m;
        mu[p] = m; rs[p] = rsqrtf(var + 1e-5f);
    }
    __syncthreads();
    for (int i = threadIdx.x; i < 32 * 192; i += 256) {
        int p = i / 192, d = i - p * 192;
        float v = (yt[d * 33 + p] - mu[p]) * rs[p] * nwf[d] + nbf[d];
        size_t addr = ((size_t)b * Lc + p0 + p) * Dd + d;
        float zv = __half2float(zsH[addr]);
        gH[addr] = __float2half(v * zv);
    }
}

// ---------------- K10: out_proj GEMM (8192 x 96 x 192) ----------------
__global__ __launch_bounds__(256) void k10_outproj(const __half* __restrict__ gH,
                                                   const float* __restrict__ wof,
                                                   const int* __restrict__ flag,
                                                   void* __restrict__ outv)
{
    __shared__ float wT[192 * 100];   // [d][c], padded
    const int bf = flag[0];
    for (int e = threadIdx.x; e < 96 * 192; e += 256) {
        int cI = e / 192, dI = e - cI * 192;
        wT[dI * 100 + cI] = wof[e];
    }
    __syncthreads();
    int r0 = blockIdx.x * 32;
    int r = threadIdx.x >> 3, cg = threadIdx.x & 7;
    const __half* grow = gH + (size_t)(r0 + r) * Dd;
    float acc[12];
#pragma unroll
    for (int i = 0; i < 12; ++i) acc[i] = 0.f;
    for (int d0 = 0; d0 < 192; d0 += 8) {
        __half2 g2[4];
        *reinterpret_cast<uint4*>(g2) = *reinterpret_cast<const uint4*>(grow + d0);
#pragma unroll
        for (int j = 0; j < 8; ++j) {
            float gf = (j & 1) ? __high2float(g2[j >> 1]) : __low2float(g2[j >> 1]);
            const float* wrow = &wT[(d0 + j) * 100 + cg * 12];
            float4 w0 = *reinterpret_cast<const float4*>(wrow);
            float4 w1 = *reinterpret_cast<const float4*>(wrow + 4);
            float4 w2 = *reinterpret_cast<const float4*>(wrow + 8);
            acc[0] += gf * w0.x; acc[1] += gf * w0.y; acc[2]  += gf * w0.z; acc[3]  += gf * w0.w;
            acc[4] += gf * w1.x; acc[5] += gf * w1.y; acc[6]  += gf * w1.z; acc[7]  += gf * w1.w;
            acc[8] += gf * w2.x; acc[9] += gf * w2.y; acc[10] += gf * w2.z; acc[11] += gf * w2.w;
        }
    }
    size_t obase = (size_t)(r0 + r) * Cc + cg * 12;
    if (bf) {
        unsigned short* o = (unsigned short*)outv;
#pragma unroll
        for (int cc = 0; cc < 12; ++cc) o[obase + cc] = f2b(acc[cc]);
    } else {
        float* o = (float*)outv;
#pragma unroll
        for (int cc = 0; cc < 12; ++cc) o[obase + cc] = acc[cc];
    }
}

extern "C" void kernel_launch(void* const* d_in, const int* in_sizes, int n_in,
                              void* d_out, int out_size, void* d_ws, size_t ws_size,
                              hipStream_t stream)
{
    (void)out_size; (void)ws_size;
    float* ws = (float*)d_ws;
    int* flag = (int*)ws;

    // converted weight region (inputs 1..11), starts at 64, ends < 131072
    int off[12]; int tot = 64;
    off[0] = 0;
    for (int i = 1; i < 12; ++i) {
        off[i] = tot;
        int n = (i < n_in) ? in_sizes[i] : 0;
        tot += (n + 63) & ~63;
    }
    float* winf = ws + off[1];
    float* cwf  = ws + off[2];
    float* cbf  = ws + off[3];
    float* xpwf = ws + off[4];
    float* dtwf = ws + off[5];
    float* dtbf = ws + off[6];
    float* alogf= ws + off[7];
    float* dsf  = ws + off[8];
    float* nwf  = ws + off[9];
    float* nbf  = ws + off[10];
    float* wof  = ws + off[11];

    const size_t BASE = 131072;
    __half* dtH = (__half*)(ws + BASE);            // 6291456 h  (B,K,Di,L)
    float*  xc  = ws + BASE + 3145728;             // 1572864 f  (B,Di,L)
    float*  uT  = ws + BASE + 4718592;             // 1572864 f  (B,Di,L) col-major
    float*  BsT = ws + BASE + 6291456;             // 524288 f   (B,K,N,L)
    float*  CsT = ws + BASE + 6815744;             // 524288 f
    float*  P   = ws + BASE + 7340032;             // 786432 f   ; alias ysT after pass3
    float*  S   = ws + BASE + 8126464;             // 786432 f   ; alias gH after k6
    __half* zsH = (__half*)(ws + BASE + 8912896);  // 1572864 h  (B,L,Di)
    float*  xi  = ws + BASE + 9699328;             // 1572864 f  (B,L,Di); dead after k2a
    float*  xiT = ws + BASE + 9699328 + 1572864;   // 1572864 f  (B,Di,L); dead after k2b
    __half* ysH = (__half*)(ws + BASE + 9699328);  // 6291456 h  (K,B,Di,L) — overlays xi/xiT
    __half* ysT = (__half*)P;                      // 1572864 h  (B,Di,L)
    __half* gH  = (__half*)S;                      // 1572864 h  (B,L,Di)
    // end = BASE + 12845056 floats = 51.9 MB

    Cv cv;
    for (int i = 0; i < 11; ++i) {
        int t = i + 1;
        cv.src[i] = (t < n_in) ? d_in[t] : d_in[0];
        cv.off[i] = off[t];
        cv.n[i]   = (t < n_in) ? in_sizes[t] : 0;
    }

    k0_detect   <<<dim3(1),    dim3(256), 0, stream>>>((const unsigned short*)d_in[0], flag);
    k0b_convert <<<dim3(144, 11), dim3(256), 0, stream>>>(cv, flag, ws);
    k1_inproj   <<<dim3(1024), dim3(256), 0, stream>>>(d_in[0], flag, winf, xi, zsH);
    k2a_transpose<<<dim3(384), dim3(256), 0, stream>>>(xi, xiT);
    k2b_conv    <<<dim3(768),  dim3(256), 0, stream>>>(xiT, cwf, cbf, xc, uT);
    k3_proj     <<<dim3(512),  dim3(256), 0, stream>>>(xc, xpwf, dtwf, dtbf, dtH, BsT, CsT);
    kscan<0>    <<<dim3(3072), dim3(256), 0, stream>>>(dtH, xc, uT, BsT, CsT, alogf, dsf, P, S, ysH);
    k6_pass2    <<<dim3(96),   dim3(256), 0, stream>>>(P, S);
    kscan<1>    <<<dim3(3072), dim3(256), 0, stream>>>(dtH, xc, uT, BsT, CsT, alogf, dsf, P, S, ysH);
    k8t         <<<dim3(384),  dim3(256), 0, stream>>>(ysH, ysT);
    k8_norm     <<<dim3(256),  dim3(256), 0, stream>>>(ysH, ysT, zsH, nwf, nbf, gH);
    k10_outproj <<<dim3(256),  dim3(256), 0, stream>>>(gH, wof, flag, d_out);
}

// Round 7
// 230.580 us; speedup vs baseline: 1.7890x; 1.7890x over previous
//
#include <hip/hip_runtime.h>
#include <hip/hip_fp16.h>
#include <math.h>

// SS2D fused block. B=2, H=W=64, L=4096, C=96, Di=192, K=4, N=16, R=6.
// Input dtype (bf16 vs f32) detected at runtime; internal compute f32 (dt/z/ys f16).
// Workspace: ~52 MB.

static constexpr int Bsz = 2;
static constexpr int Lc  = 4096;
static constexpr int Cc  = 96;
static constexpr int Dd  = 192;
static constexpr int Kk  = 4;
static constexpr int NC  = 32;     // chunks of 128 steps

__device__ __forceinline__ float bu(unsigned short v) {
    return __uint_as_float((unsigned int)v << 16);
}
__device__ __forceinline__ unsigned short f2b(float f) {
    unsigned int u = __float_as_uint(f);
    return (unsigned short)((u + 0x7fffu + ((u >> 16) & 1u)) >> 16);
}

// DPP 16-lane row reduction: 4 full-rate VALU adds, no DS pipe.
template<int CTRL>
__device__ __forceinline__ float dppadd(float x) {
    return x + __int_as_float(__builtin_amdgcn_update_dpp(
        0, __float_as_int(x), CTRL, 0xf, 0xf, true));
}
__device__ __forceinline__ float red16(float x) {
    x = dppadd<0xB1>(x);    // quad_perm [1,0,3,2]  (xor 1)
    x = dppadd<0x4E>(x);    // quad_perm [2,3,0,1]  (xor 2)
    x = dppadd<0x124>(x);   // row_ror:4
    x = dppadd<0x128>(x);   // row_ror:8
    return x;
}

// ---------------- K0: dtype detector (bf16 vs f32) ----------------
__global__ __launch_bounds__(256) void k0_detect(const unsigned short* __restrict__ x,
                                                 int* __restrict__ flag)
{
    __shared__ int s[256];
    int cnt = 0;
    for (int i = threadIdx.x; i < 4096; i += 256) {
        int e = (x[i] >> 7) & 0xFF;
        cnt += (e >= 118 && e <= 131) ? 1 : 0;
    }
    s[threadIdx.x] = cnt;
    __syncthreads();
    for (int st = 128; st > 0; st >>= 1) {
        if (threadIdx.x < st) s[threadIdx.x] += s[threadIdx.x + st];
        __syncthreads();
    }
    if (threadIdx.x == 0) flag[0] = (s[0] >= 3072) ? 1 : 0;
}

// ---------------- K0b: convert weight inputs (1..11) to canonical f32 ----------------
struct Cv {
    const void* src[11];
    int off[11];
    int n[11];
};
__global__ __launch_bounds__(256) void k0b_convert(Cv cv, const int* __restrict__ flag,
                                                   float* __restrict__ dstbase)
{
    int bf = flag[0];
    int t = blockIdx.y;
    int i = blockIdx.x * 256 + threadIdx.x;
    if (i >= cv.n[t]) return;
    float v;
    if (bf) v = bu(((const unsigned short*)cv.src[t])[i]);
    else    v = ((const float*)cv.src[t])[i];
    dstbase[cv.off[t] + i] = v;
}

// ---------------- K1: in_proj GEMM (8192x384x96), split xi / silu(z) ----------------
__global__ __launch_bounds__(256) void k1_inproj(const void* __restrict__ xraw,
                                                 const int* __restrict__ flag,
                                                 const float* __restrict__ wf,
                                                 float* __restrict__ xi, __half* __restrict__ zs)
{
    __shared__ float xT[32 * 97];
    __shared__ float wT[96 * 97];
    const int bf = flag[0];
    int tile = blockIdx.x >> 2, jq = blockIdx.x & 3;
    int b = tile >> 7;
    int l0 = (tile & 127) << 5;
    int j0 = jq * 96;
    for (int e = threadIdx.x; e < 32 * 96; e += 256) {
        int i = e / 96, c = e % 96;
        size_t idx = (size_t)(b * Lc + l0 + i) * Cc + c;
        xT[i * 97 + c] = bf ? bu(((const unsigned short*)xraw)[idx])
                            : ((const float*)xraw)[idx];
    }
    for (int e = threadIdx.x; e < 96 * 96; e += 256) {
        int j = e / 96, c = e % 96;
        wT[j * 97 + c] = wf[(size_t)(j0 + j) * Cc + c];
    }
    __syncthreads();
    int jj = threadIdx.x & 31, ll = threadIdx.x >> 5;
    float acc[4][3];
#pragma unroll
    for (int i = 0; i < 4; i++)
#pragma unroll
        for (int m = 0; m < 3; m++) acc[i][m] = 0.f;
    for (int c = 0; c < 96; ++c) {
        float xv[4], wv[3];
#pragma unroll
        for (int i = 0; i < 4; i++) xv[i] = xT[(ll * 4 + i) * 97 + c];
#pragma unroll
        for (int m = 0; m < 3; m++) wv[m] = wT[(jj + 32 * m) * 97 + c];
#pragma unroll
        for (int i = 0; i < 4; i++)
#pragma unroll
            for (int m = 0; m < 3; m++) acc[i][m] += xv[i] * wv[m];
    }
#pragma unroll
    for (int i = 0; i < 4; i++) {
        int l = l0 + ll * 4 + i;
#pragma unroll
        for (int m = 0; m < 3; m++) {
            int j = j0 + jj + 32 * m;
            float v = acc[i][m];
            if (j < Dd) xi[(size_t)(b * Lc + l) * Dd + j] = v;
            else        zs[(size_t)(b * Lc + l) * Dd + (j - Dd)] = __float2half(v / (1.f + __expf(-v)));
        }
    }
}

// ---------------- K2a: transpose xi (B,L,Di) -> xiT (B,Di,L) ----------------
__global__ __launch_bounds__(256) void k2a_transpose(const float* __restrict__ xi,
                                                     float* __restrict__ xiT)
{
    __shared__ float t[64 * 65];
    int bid = blockIdx.x;
    int lq = bid & 63, dq = (bid >> 6) % 3, b = bid / 192;
    int l0 = lq * 64, d0 = dq * 64;
    for (int e = threadIdx.x; e < 4096; e += 256) {
        int i = e >> 6, j = e & 63;
        t[i * 65 + j] = xi[(size_t)(b * Lc + l0 + i) * Dd + d0 + j];
    }
    __syncthreads();
    for (int e = threadIdx.x; e < 4096; e += 256) {
        int j = e >> 6, i = e & 63;
        xiT[(size_t)(b * Dd + d0 + j) * Lc + l0 + i] = t[i * 65 + j];
    }
}

// -------- K2b: depthwise 3x3 conv + bias + SiLU (channel-first), writes xc and uT --------
__global__ __launch_bounds__(256) void k2b_conv(const float* __restrict__ xiT,
                                                const float* __restrict__ cwf,
                                                const float* __restrict__ cbf,
                                                float* __restrict__ xc,
                                                float* __restrict__ uT)
{
    __shared__ float inl[34 * 66];   // rows h0-1..h0+32, cols zero-padded
    __shared__ float outl[32 * 65];
    int bid = blockIdx.x;
    int half = bid & 1;
    int d = (bid >> 1) % Dd;
    int b = bid / (2 * Dd);
    int h0 = half * 32;
    const float* src = xiT + (size_t)(b * Dd + d) * Lc;
    for (int r = threadIdx.x; r < 34; r += 256) {
        inl[r * 66 + 0] = 0.f;
        inl[r * 66 + 65] = 0.f;
    }
    for (int e = threadIdx.x; e < 34 * 64; e += 256) {
        int row = e >> 6, w = e & 63;
        int h = h0 - 1 + row;
        inl[row * 66 + 1 + w] = (h >= 0 && h < 64) ? src[h * 64 + w] : 0.f;
    }
    __syncthreads();
    float wgt[9];
#pragma unroll
    for (int t = 0; t < 9; t++) wgt[t] = cwf[d * 9 + t];
    float bias = cbf[d];
    int hs = threadIdx.x >> 6, w = threadIdx.x & 63;
    float* dstrow = xc + (size_t)(b * Dd + d) * Lc;
#pragma unroll
    for (int it = 0; it < 8; ++it) {
        int hh = it * 4 + hs;
        float acc = bias;
#pragma unroll
        for (int dy = 0; dy < 3; ++dy) {
            const float* rp = &inl[(hh + dy) * 66 + w];
#pragma unroll
            for (int dx = 0; dx < 3; ++dx)
                acc += rp[dx] * wgt[dy * 3 + dx];
        }
        float s = acc / (1.f + __expf(-acc));
        dstrow[(h0 + hh) * 64 + w] = s;
        outl[hh * 65 + w] = s;
    }
    __syncthreads();
    float* udst = uT + (size_t)(b * Dd + d) * Lc;
    for (int e = threadIdx.x; e < 2048; e += 256) {
        int w2 = e >> 5, hh2 = e & 31;
        udst[w2 * 64 + h0 + hh2] = outl[hh2 * 65 + w2];
    }
}

// -------- K3: per-direction projection (38 outs) + dt-proj + softplus --------
__global__ __launch_bounds__(256) void k3_proj(const float* __restrict__ xc,
                                               const float* __restrict__ xpwf,
                                               const float* __restrict__ dtwf,
                                               const float* __restrict__ dtbf,
                                               __half* __restrict__ dtH,
                                               float* __restrict__ BsT, float* __restrict__ CsT)
{
    __shared__ float Wl[192 * 40];
    __shared__ float dtWl[192 * 8];
    __shared__ float biasl[192];
    __shared__ float rawq[4][64 * 41];
    int bid = blockIdx.x;
    int pt = bid & 63, k = (bid >> 6) & 3, b = bid >> 8;
    bool colm = (k & 1);
    int s0 = pt * 64;
    for (int e = threadIdx.x; e < 38 * 192; e += 256) {
        int cp = e / 192, d = e % 192;
        Wl[d * 40 + cp] = xpwf[(size_t)(k * 38 + cp) * 192 + d];
    }
    for (int e = threadIdx.x; e < 2 * 192; e += 256) {
        Wl[(e >> 1) * 40 + 38 + (e & 1)] = 0.f;
    }
    for (int e = threadIdx.x; e < 192 * 6; e += 256) {
        int d = e / 6, r = e % 6;
        dtWl[d * 8 + r] = dtwf[(size_t)(k * 192 + d) * 6 + r];
    }
    for (int e = threadIdx.x; e < 192; e += 256) biasl[e] = dtbf[k * 192 + e];
    __syncthreads();
    int pi = threadIdx.x & 63, q = threadIdx.x >> 6;
    int pos = colm ? (pi * 64 + pt) : (pt * 64 + pi);
    float acc[40];
#pragma unroll
    for (int i = 0; i < 40; i++) acc[i] = 0.f;
    const float* xrow = xc + (size_t)b * Dd * Lc + pos;
    for (int dd = 0; dd < 48; ++dd) {
        int d = q * 48 + dd;
        float xv = xrow[(size_t)d * Lc];
#pragma unroll
        for (int c4 = 0; c4 < 10; ++c4) {
            float4 w4 = *reinterpret_cast<const float4*>(&Wl[d * 40 + c4 * 4]);
            acc[c4 * 4 + 0] += w4.x * xv; acc[c4 * 4 + 1] += w4.y * xv;
            acc[c4 * 4 + 2] += w4.z * xv; acc[c4 * 4 + 3] += w4.w * xv;
        }
    }
    float* myraw = &rawq[q][pi * 41];
#pragma unroll
    for (int i = 0; i < 40; i++) myraw[i] = acc[i];
    __syncthreads();
    for (int e = threadIdx.x; e < 64 * 40; e += 256) {
        int p = e / 40, cp = e % 40;
        rawq[0][p * 41 + cp] = rawq[0][p * 41 + cp] + rawq[1][p * 41 + cp]
                             + rawq[2][p * 41 + cp] + rawq[3][p * 41 + cp];
    }
    __syncthreads();
    // B/C transposed: [ (b,k) ][ n ][ t ]  (f32)
    for (int e = threadIdx.x; e < 64 * 16; e += 256) {
        int n = e >> 6, p = e & 63;
        size_t base = ((size_t)((b * Kk + k) * 16 + n)) * Lc + s0 + p;
        BsT[base] = rawq[0][p * 41 + 6 + n];
        CsT[base] = rawq[0][p * 41 + 22 + n];
    }
    for (int dd = 0; dd < 48; ++dd) {
        int d = q * 48 + dd;
        float s = biasl[d];
#pragma unroll
        for (int r = 0; r < 6; r++) s += rawq[0][pi * 41 + r] * dtWl[d * 8 + r];
        float sp = fmaxf(s, 0.f) + log1pf(__expf(-fabsf(s)));
        dtH[((size_t)(b * Kk + k) * Dd + d) * Lc + s0 + pi] = __float2half(sp);
    }
}

// ---------------- KSCAN: chunked selective scan, LDS-staged double buffer ----------------
// Block = 16 d-lanes x 16 n-lanes; chunk = 128 steps = 2 LDS tiles of 64 steps.
// LDS row stride 68 floats -> bank stride 4 -> worst 2-way conflict (free).
template<int REV, int PASS3>
__device__ __forceinline__ void scan_run(const float* __restrict__ ubase,
                                         const __half* __restrict__ dbase,
                                         const float* __restrict__ Bbase,
                                         const float* __restrict__ Cbase,
                                         float* u0, float* u1, float* b0, float* b1,
                                         float* c0, float* c1, __half* e0, __half* e1,
                                         int sd, int sc, int dl, int n, int c,
                                         float An, float Dsv,
                                         float* __restrict__ P, float* __restrict__ S,
                                         size_t pidx, __half* __restrict__ yrow)
{
    const int t0 = c * 128;
    const int tg0 = REV ? (Lc - 64 - t0) : t0;
    const int tg1 = REV ? (Lc - 128 - t0) : (t0 + 64);

    float h = PASS3 ? P[pidx] : 0.f;
    float sdt = 0.f, ystash = 0.f;

    // ---- stage tile 0 ----
    float4 ru = *reinterpret_cast<const float4*>(ubase + tg0 + sc);
    float4 rb = *reinterpret_cast<const float4*>(Bbase + tg0 + sc);
    float4 rc{};
    if (PASS3) rc = *reinterpret_cast<const float4*>(Cbase + tg0 + sc);
    uint2 rd = *reinterpret_cast<const uint2*>(dbase + tg0 + sc);
    *reinterpret_cast<float4*>(u0 + sd * 68 + sc) = ru;
    *reinterpret_cast<float4*>(b0 + sd * 68 + sc) = rb;
    if (PASS3) *reinterpret_cast<float4*>(c0 + sd * 68 + sc) = rc;
    *reinterpret_cast<uint2*>(e0 + sd * 68 + sc) = rd;
    __syncthreads();

    // ---- issue tile 1 loads (overlap with compute of tile 0) ----
    ru = *reinterpret_cast<const float4*>(ubase + tg1 + sc);
    rb = *reinterpret_cast<const float4*>(Bbase + tg1 + sc);
    if (PASS3) rc = *reinterpret_cast<const float4*>(Cbase + tg1 + sc);
    rd = *reinterpret_cast<const uint2*>(dbase + tg1 + sc);

#define SS2D_COMPUTE(UU, BB, CC, EE, IBASE)                                     \
    {                                                                           \
        _Pragma("unroll")                                                       \
        for (int qi = 0; qi < 16; ++qi) {                                       \
            const int col4 = REV ? (60 - qi * 4) : (qi * 4);                    \
            float4 uq = *reinterpret_cast<const float4*>(UU + dl * 68 + col4);  \
            float4 bq = *reinterpret_cast<const float4*>(BB + n * 68 + col4);   \
            float4 cq{};                                                        \
            if (PASS3) cq = *reinterpret_cast<const float4*>(CC + n * 68 + col4);\
            uint2 dq = *reinterpret_cast<const uint2*>(EE + dl * 68 + col4);    \
            const __half2* dh2 = reinterpret_cast<const __half2*>(&dq);         \
            _Pragma("unroll")                                                   \
            for (int j = 0; j < 4; ++j) {                                       \
                const int e = REV ? (3 - j) : j;                                \
                float dtv = (e & 1) ? __high2float(dh2[e >> 1])                 \
                                    : __low2float(dh2[e >> 1]);                 \
                float uv = reinterpret_cast<const float*>(&uq)[e];              \
                float bv = reinterpret_cast<const float*>(&bq)[e];              \
                float a = __expf(dtv * An);                                     \
                if (!PASS3) sdt += dtv;                                         \
                h = a * h + (dtv * uv) * bv;                                    \
                if (PASS3) {                                                    \
                    float cv = reinterpret_cast<const float*>(&cq)[e];          \
                    float yv = red16(h * cv);                                   \
                    const int i15 = (qi & 3) * 4 + j;                           \
                    if (i15 == n) ystash = yv + uv * Dsv;                       \
                    if (i15 == 15) {                                            \
                        int tb = t0 + (IBASE) + (qi & ~3) * 4 + n;              \
                        int aw = REV ? (Lc - 1 - tb) : tb;                      \
                        yrow[aw] = __float2half(ystash);                        \
                    }                                                           \
                }                                                               \
            }                                                                   \
        }                                                                       \
    }

    SS2D_COMPUTE(u0, b0, c0, e0, 0);

    // ---- write tile 1 to LDS (vmcnt wait absorbed here) ----
    *reinterpret_cast<float4*>(u1 + sd * 68 + sc) = ru;
    *reinterpret_cast<float4*>(b1 + sd * 68 + sc) = rb;
    if (PASS3) *reinterpret_cast<float4*>(c1 + sd * 68 + sc) = rc;
    *reinterpret_cast<uint2*>(e1 + sd * 68 + sc) = rd;
    __syncthreads();

    SS2D_COMPUTE(u1, b1, c1, e1, 64);
#undef SS2D_COMPUTE

    if (!PASS3) {
        P[pidx] = __expf(An * sdt);
        S[pidx] = h;
    }
}

template<int PASS3>
__global__ __launch_bounds__(256) void kscan(const __half* __restrict__ dtH,
                                             const float* __restrict__ xc,
                                             const float* __restrict__ uT,
                                             const float* __restrict__ BsT,
                                             const float* __restrict__ CsT,
                                             const float* __restrict__ alogf,
                                             const float* __restrict__ dsf,
                                             float* __restrict__ P,
                                             float* __restrict__ S,
                                             __half* __restrict__ ysH)
{
    __shared__ float uL[2][16 * 68];
    __shared__ float bL[2][16 * 68];
    __shared__ float cL[2][PASS3 ? 16 * 68 : 4];
    __shared__ __half dL[2][16 * 68];

    int c  = blockIdx.x & 31;
    int t1 = blockIdx.x >> 5;          // 0..95
    int dg = t1 % 12;
    int kk = (t1 / 12) & 3;
    int b  = t1 / 48;
    int n  = threadIdx.x & 15, dl = threadIdx.x >> 4;
    int d  = dg * 16 + dl;

    int sd = dl;          // staging row (d-row for u/dt, n-row for B/C)
    int sc = n * 4;       // staging col (floats/halfs)

    const float* ubz = ((kk & 1) ? uT : xc) + (size_t)b * Dd * Lc;
    const float*  ubase = ubz + (size_t)(dg * 16 + sd) * Lc;
    const __half* dbase = dtH + ((size_t)((b * Kk + kk) * Dd + dg * 16 + sd)) * Lc;
    const float*  Bbase = BsT + ((size_t)((b * Kk + kk) * 16 + sd)) * Lc;
    const float*  Cbase = CsT + ((size_t)((b * Kk + kk) * 16 + sd)) * Lc;

    float An  = -__expf(alogf[(kk * Dd + d) * 16 + n]);
    float Dsv = PASS3 ? dsf[kk * Dd + d] : 0.f;
    size_t pidx = (((size_t)(b * Kk + kk) * Dd + d) * NC + c) * 16 + n;
    __half* yrow = PASS3 ? ysH + ((size_t)(kk * Bsz + b) * Dd + d) * Lc : nullptr;

    if (kk >= 2)
        scan_run<1, PASS3>(ubase, dbase, Bbase, Cbase,
                           uL[0], uL[1], bL[0], bL[1], cL[0], cL[1], dL[0], dL[1],
                           sd, sc, dl, n, c, An, Dsv, P, S, pidx, yrow);
    else
        scan_run<0, PASS3>(ubase, dbase, Bbase, Cbase,
                           uL[0], uL[1], bL[0], bL[1], cL[0], cL[1], dL[0], dL[1],
                           sd, sc, dl, n, c, An, Dsv, P, S, pidx, yrow);
}

// ---------------- K6: chunk-level scan; carry-in written in place over P ----------------
__global__ __launch_bounds__(256) void k6_pass2(float* __restrict__ P, const float* __restrict__ S)
{
    int g = blockIdx.x * 256 + threadIdx.x;   // 24576
    int n = g & 15;
    int chain = g >> 4;
    size_t base = (size_t)chain * NC * 16 + n;
    float h = 0.f;
    for (int c = 0; c < NC; ++c) {
        size_t id = base + (size_t)c * 16;
        float p = P[id], s = S[id];
        P[id] = h;
        h = p * h + s;
    }
}

// ---------------- K8t: ysT = transpose(ys1 + ys3) per (b,d) ----------------
__global__ __launch_bounds__(256) void k8t(const __half* __restrict__ ysH,
                                           __half* __restrict__ ysT)
{
    __shared__ float t[64 * 65];
    int bid = blockIdx.x;
    int d = bid % Dd, b = bid / Dd;
    const __half* y1 = ysH + ((size_t)(1 * Bsz + b) * Dd + d) * Lc;
    const __half* y3 = ysH + ((size_t)(3 * Bsz + b) * Dd + d) * Lc;
    __half* dst = ysT + ((size_t)b * Dd + d) * Lc;
    for (int e = threadIdx.x; e < 4096; e += 256)
        t[(e >> 6) * 65 + (e & 63)] = __half2float(y1[e]) + __half2float(y3[e]);
    __syncthreads();
    for (int e = threadIdx.x; e < 4096; e += 256)
        dst[e] = __float2half(t[(e & 63) * 65 + (e >> 6)]);
}

// ---------------- K8: merge + LayerNorm + SiLU(z) gate -> gH ----------------
__global__ __launch_bounds__(256) void k8_norm(const __half* __restrict__ ysH,
                                               const __half* __restrict__ ysT,
                                               const __half* __restrict__ zsH,
                                               const float* __restrict__ nwf,
                                               const float* __restrict__ nbf,
                                               __half* __restrict__ gH)
{
    __shared__ float yt[192 * 33];
    __shared__ float ps1[8 * 32], ps2[8 * 32];
    __shared__ float mu[32], rs[32];
    int bid = blockIdx.x;
    int pt = bid & 127, b = bid >> 7;
    int p0 = pt * 32;
    for (int e = threadIdx.x; e < 192 * 32; e += 256) {
        int d = e >> 5, p = e & 31;
        size_t r0 = ((size_t)(0 * Bsz + b) * Dd + d) * Lc + p0 + p;
        size_t r2 = ((size_t)(2 * Bsz + b) * Dd + d) * Lc + p0 + p;
        size_t rt = ((size_t)b * Dd + d) * Lc + p0 + p;
        yt[d * 33 + p] = __half2float(ysH[r0]) + __half2float(ysH[r2]) + __half2float(ysT[rt]);
    }
    __syncthreads();
    {
        int p = threadIdx.x & 31, q = threadIdx.x >> 5;
        float s1 = 0.f, s2 = 0.f;
        for (int dd = 0; dd < 24; ++dd) {
            float v = yt[(q * 24 + dd) * 33 + p];
            s1 += v; s2 += v * v;
        }
        ps1[q * 32 + p] = s1; ps2[q * 32 + p] = s2;
    }
    __syncthreads();
    if (threadIdx.x < 32) {
        int p = threadIdx.x;
        float s1 = 0.f, s2 = 0.f;
        for (int q = 0; q < 8; ++q) { s1 += ps1[q * 32 + p]; s2 += ps2[q * 32 + p]; }
        float m = s1 * (1.f / 192.f);
        float var = s2 * (1.f / 192.f) - m * m;
        mu[p] = m; rs[p] = rsqrtf(var + 1e-5f);
    }
    __syncthreads();
    for (int i = threadIdx.x; i < 32 * 192; i += 256) {
        int p = i / 192, d = i - p * 192;
        float v = (yt[d * 33 + p] - mu[p]) * rs[p] * nwf[d] + nbf[d];
        size_t addr = ((size_t)b * Lc + p0 + p) * Dd + d;
        float zv = __half2float(zsH[addr]);
        gH[addr] = __float2half(v * zv);
    }
}

// ---------------- K10: out_proj GEMM (8192 x 96 x 192) ----------------
__global__ __launch_bounds__(256) void k10_outproj(const __half* __restrict__ gH,
                                                   const float* __restrict__ wof,
                                                   const int* __restrict__ flag,
                                                   void* __restrict__ outv)
{
    __shared__ float wT[192 * 100];   // [d][c], padded
    const int bf = flag[0];
    for (int e = threadIdx.x; e < 96 * 192; e += 256) {
        int cI = e / 192, dI = e - cI * 192;
        wT[dI * 100 + cI] = wof[e];
    }
    __syncthreads();
    int r0 = blockIdx.x * 32;
    int r = threadIdx.x >> 3, cg = threadIdx.x & 7;
    const __half* grow = gH + (size_t)(r0 + r) * Dd;
    float acc[12];
#pragma unroll
    for (int i = 0; i < 12; ++i) acc[i] = 0.f;
    for (int d0 = 0; d0 < 192; d0 += 8) {
        __half2 g2[4];
        *reinterpret_cast<uint4*>(g2) = *reinterpret_cast<const uint4*>(grow + d0);
#pragma unroll
        for (int j = 0; j < 8; ++j) {
            float gf = (j & 1) ? __high2float(g2[j >> 1]) : __low2float(g2[j >> 1]);
            const float* wrow = &wT[(d0 + j) * 100 + cg * 12];
            float4 w0 = *reinterpret_cast<const float4*>(wrow);
            float4 w1 = *reinterpret_cast<const float4*>(wrow + 4);
            float4 w2 = *reinterpret_cast<const float4*>(wrow + 8);
            acc[0] += gf * w0.x; acc[1] += gf * w0.y; acc[2]  += gf * w0.z; acc[3]  += gf * w0.w;
            acc[4] += gf * w1.x; acc[5] += gf * w1.y; acc[6]  += gf * w1.z; acc[7]  += gf * w1.w;
            acc[8] += gf * w2.x; acc[9] += gf * w2.y; acc[10] += gf * w2.z; acc[11] += gf * w2.w;
        }
    }
    size_t obase = (size_t)(r0 + r) * Cc + cg * 12;
    if (bf) {
        unsigned short* o = (unsigned short*)outv;
#pragma unroll
        for (int cc = 0; cc < 12; ++cc) o[obase + cc] = f2b(acc[cc]);
    } else {
        float* o = (float*)outv;
#pragma unroll
        for (int cc = 0; cc < 12; ++cc) o[obase + cc] = acc[cc];
    }
}

extern "C" void kernel_launch(void* const* d_in, const int* in_sizes, int n_in,
                              void* d_out, int out_size, void* d_ws, size_t ws_size,
                              hipStream_t stream)
{
    (void)out_size; (void)ws_size;
    float* ws = (float*)d_ws;
    int* flag = (int*)ws;

    // converted weight region (inputs 1..11), starts at 64, ends < 131072
    int off[12]; int tot = 64;
    off[0] = 0;
    for (int i = 1; i < 12; ++i) {
        off[i] = tot;
        int n = (i < n_in) ? in_sizes[i] : 0;
        tot += (n + 63) & ~63;
    }
    float* winf = ws + off[1];
    float* cwf  = ws + off[2];
    float* cbf  = ws + off[3];
    float* xpwf = ws + off[4];
    float* dtwf = ws + off[5];
    float* dtbf = ws + off[6];
    float* alogf= ws + off[7];
    float* dsf  = ws + off[8];
    float* nwf  = ws + off[9];
    float* nbf  = ws + off[10];
    float* wof  = ws + off[11];

    const size_t BASE = 131072;
    __half* dtH = (__half*)(ws + BASE);            // 6291456 h  (B,K,Di,L)
    float*  xc  = ws + BASE + 3145728;             // 1572864 f  (B,Di,L)
    float*  uT  = ws + BASE + 4718592;             // 1572864 f  (B,Di,L) col-major
    float*  BsT = ws + BASE + 6291456;             // 524288 f   (B,K,N,L)
    float*  CsT = ws + BASE + 6815744;             // 524288 f
    float*  P   = ws + BASE + 7340032;             // 786432 f   ; alias ysT after pass3
    float*  S   = ws + BASE + 8126464;             // 786432 f   ; alias gH after k6
    __half* zsH = (__half*)(ws + BASE + 8912896);  // 1572864 h  (B,L,Di)
    float*  xi  = ws + BASE + 9699328;             // 1572864 f  (B,L,Di); dead after k2a
    float*  xiT = ws + BASE + 9699328 + 1572864;   // 1572864 f  (B,Di,L); dead after k2b
    __half* ysH = (__half*)(ws + BASE + 9699328);  // 6291456 h  (K,B,Di,L) — overlays xi/xiT
    __half* ysT = (__half*)P;                      // 1572864 h  (B,Di,L)
    __half* gH  = (__half*)S;                      // 1572864 h  (B,L,Di)
    // end = BASE + 12845056 floats = 51.9 MB

    Cv cv;
    for (int i = 0; i < 11; ++i) {
        int t = i + 1;
        cv.src[i] = (t < n_in) ? d_in[t] : d_in[0];
        cv.off[i] = off[t];
        cv.n[i]   = (t < n_in) ? in_sizes[t] : 0;
    }

    k0_detect   <<<dim3(1),    dim3(256), 0, stream>>>((const unsigned short*)d_in[0], flag);
    k0b_convert <<<dim3(144, 11), dim3(256), 0, stream>>>(cv, flag, ws);
    k1_inproj   <<<dim3(1024), dim3(256), 0, stream>>>(d_in[0], flag, winf, xi, zsH);
    k2a_transpose<<<dim3(384), dim3(256), 0, stream>>>(xi, xiT);
    k2b_conv    <<<dim3(768),  dim3(256), 0, stream>>>(xiT, cwf, cbf, xc, uT);
    k3_proj     <<<dim3(512),  dim3(256), 0, stream>>>(xc, xpwf, dtwf, dtbf, dtH, BsT, CsT);
    kscan<0>    <<<dim3(3072), dim3(256), 0, stream>>>(dtH, xc, uT, BsT, CsT, alogf, dsf, P, S, ysH);
    k6_pass2    <<<dim3(96),   dim3(256), 0, stream>>>(P, S);
    kscan<1>    <<<dim3(3072), dim3(256), 0, stream>>>(dtH, xc, uT, BsT, CsT, alogf, dsf, P, S, ysH);
    k8t         <<<dim3(384),  dim3(256), 0, stream>>>(ysH, ysT);
    k8_norm     <<<dim3(256),  dim3(256), 0, stream>>>(ysH, ysT, zsH, nwf, nbf, gH);
    k10_outproj <<<dim3(256),  dim3(256), 0, stream>>>(gH, wof, flag, d_out);
}

// Round 8
// 222.103 us; speedup vs baseline: 1.8573x; 1.0382x over previous
//
#include <hip/hip_runtime.h>
#include <hip/hip_fp16.h>
#include <math.h>

// SS2D fused block. B=2, H=W=64, L=4096, C=96, Di=192, K=4, N=16, R=6.
// Input dtype (bf16 vs f32) detected at runtime; internal compute f32 (dt/z/ys f16).
// Workspace: ~52.1 MB.

static constexpr int Bsz = 2;
static constexpr int Lc  = 4096;
static constexpr int Cc  = 96;
static constexpr int Dd  = 192;
static constexpr int Kk  = 4;
static constexpr int NC  = 32;     // chunks of 128 steps

__device__ __forceinline__ float bu(unsigned short v) {
    return __uint_as_float((unsigned int)v << 16);
}
__device__ __forceinline__ unsigned short f2b(float f) {
    unsigned int u = __float_as_uint(f);
    return (unsigned short)((u + 0x7fffu + ((u >> 16) & 1u)) >> 16);
}

// DPP 16-lane row reduction: 4 full-rate VALU adds, no DS pipe.
template<int CTRL>
__device__ __forceinline__ float dppadd(float x) {
    return x + __int_as_float(__builtin_amdgcn_update_dpp(
        0, __float_as_int(x), CTRL, 0xf, 0xf, true));
}
__device__ __forceinline__ float red16(float x) {
    x = dppadd<0xB1>(x);    // quad_perm [1,0,3,2]  (xor 1)
    x = dppadd<0x4E>(x);    // quad_perm [2,3,0,1]  (xor 2)
    x = dppadd<0x124>(x);   // row_ror:4
    x = dppadd<0x128>(x);   // row_ror:8
    return x;
}

// ---------------- K0: dtype detector (bf16 vs f32) ----------------
__global__ __launch_bounds__(256) void k0_detect(const unsigned short* __restrict__ x,
                                                 int* __restrict__ flag)
{
    __shared__ int s[256];
    int cnt = 0;
    for (int i = threadIdx.x; i < 4096; i += 256) {
        int e = (x[i] >> 7) & 0xFF;
        cnt += (e >= 118 && e <= 131) ? 1 : 0;
    }
    s[threadIdx.x] = cnt;
    __syncthreads();
    for (int st = 128; st > 0; st >>= 1) {
        if (threadIdx.x < st) s[threadIdx.x] += s[threadIdx.x + st];
        __syncthreads();
    }
    if (threadIdx.x == 0) flag[0] = (s[0] >= 3072) ? 1 : 0;
}

// ---------------- K0b: convert weight inputs (1..11) to canonical f32 ----------------
struct Cv {
    const void* src[11];
    int off[11];
    int n[11];
};
__global__ __launch_bounds__(256) void k0b_convert(Cv cv, const int* __restrict__ flag,
                                                   float* __restrict__ dstbase)
{
    int bf = flag[0];
    int t = blockIdx.y;
    int i = blockIdx.x * 256 + threadIdx.x;
    if (i >= cv.n[t]) return;
    float v;
    if (bf) v = bu(((const unsigned short*)cv.src[t])[i]);
    else    v = ((const float*)cv.src[t])[i];
    dstbase[cv.off[t] + i] = v;
}

// ---------------- K3w: build Wg[k][d][40] = x_proj_weight[k][cp][d] (pad->0) ----------------
__global__ __launch_bounds__(256) void k3w_prep(const float* __restrict__ xpwf,
                                                float* __restrict__ Wg)
{
    int idx = blockIdx.x * 256 + threadIdx.x;   // 30720 total
    if (idx >= 4 * 192 * 40) return;
    int cp = idx % 40;
    int d  = (idx / 40) % 192;
    int k  = idx / 7680;
    Wg[idx] = (cp < 38) ? xpwf[(size_t)(k * 38 + cp) * 192 + d] : 0.f;
}

// ---------------- K1: in_proj GEMM (8192x384x96), split xi / silu(z) ----------------
__global__ __launch_bounds__(256) void k1_inproj(const void* __restrict__ xraw,
                                                 const int* __restrict__ flag,
                                                 const float* __restrict__ wf,
                                                 float* __restrict__ xi, __half* __restrict__ zs)
{
    __shared__ float xT[32 * 97];
    __shared__ float wT[96 * 97];
    const int bf = flag[0];
    int tile = blockIdx.x >> 2, jq = blockIdx.x & 3;
    int b = tile >> 7;
    int l0 = (tile & 127) << 5;
    int j0 = jq * 96;
    for (int e = threadIdx.x; e < 32 * 96; e += 256) {
        int i = e / 96, c = e % 96;
        size_t idx = (size_t)(b * Lc + l0 + i) * Cc + c;
        xT[i * 97 + c] = bf ? bu(((const unsigned short*)xraw)[idx])
                            : ((const float*)xraw)[idx];
    }
    for (int e = threadIdx.x; e < 96 * 96; e += 256) {
        int j = e / 96, c = e % 96;
        wT[j * 97 + c] = wf[(size_t)(j0 + j) * Cc + c];
    }
    __syncthreads();
    int jj = threadIdx.x & 31, ll = threadIdx.x >> 5;
    float acc[4][3];
#pragma unroll
    for (int i = 0; i < 4; i++)
#pragma unroll
        for (int m = 0; m < 3; m++) acc[i][m] = 0.f;
    for (int c = 0; c < 96; ++c) {
        float xv[4], wv[3];
#pragma unroll
        for (int i = 0; i < 4; i++) xv[i] = xT[(ll * 4 + i) * 97 + c];
#pragma unroll
        for (int m = 0; m < 3; m++) wv[m] = wT[(jj + 32 * m) * 97 + c];
#pragma unroll
        for (int i = 0; i < 4; i++)
#pragma unroll
            for (int m = 0; m < 3; m++) acc[i][m] += xv[i] * wv[m];
    }
#pragma unroll
    for (int i = 0; i < 4; i++) {
        int l = l0 + ll * 4 + i;
#pragma unroll
        for (int m = 0; m < 3; m++) {
            int j = j0 + jj + 32 * m;
            float v = acc[i][m];
            if (j < Dd) xi[(size_t)(b * Lc + l) * Dd + j] = v;
            else        zs[(size_t)(b * Lc + l) * Dd + (j - Dd)] = __float2half(v / (1.f + __expf(-v)));
        }
    }
}

// ---------------- K2a: transpose xi (B,L,Di) -> xiT (B,Di,L) ----------------
__global__ __launch_bounds__(256) void k2a_transpose(const float* __restrict__ xi,
                                                     float* __restrict__ xiT)
{
    __shared__ float t[64 * 65];
    int bid = blockIdx.x;
    int lq = bid & 63, dq = (bid >> 6) % 3, b = bid / 192;
    int l0 = lq * 64, d0 = dq * 64;
    for (int e = threadIdx.x; e < 4096; e += 256) {
        int i = e >> 6, j = e & 63;
        t[i * 65 + j] = xi[(size_t)(b * Lc + l0 + i) * Dd + d0 + j];
    }
    __syncthreads();
    for (int e = threadIdx.x; e < 4096; e += 256) {
        int j = e >> 6, i = e & 63;
        xiT[(size_t)(b * Dd + d0 + j) * Lc + l0 + i] = t[i * 65 + j];
    }
}

// -------- K2b: depthwise 3x3 conv + bias + SiLU (channel-first), writes xc and uT --------
__global__ __launch_bounds__(256) void k2b_conv(const float* __restrict__ xiT,
                                                const float* __restrict__ cwf,
                                                const float* __restrict__ cbf,
                                                float* __restrict__ xc,
                                                float* __restrict__ uT)
{
    __shared__ float inl[34 * 66];   // rows h0-1..h0+32, cols zero-padded
    __shared__ float outl[32 * 65];
    int bid = blockIdx.x;
    int half = bid & 1;
    int d = (bid >> 1) % Dd;
    int b = bid / (2 * Dd);
    int h0 = half * 32;
    const float* src = xiT + (size_t)(b * Dd + d) * Lc;
    for (int r = threadIdx.x; r < 34; r += 256) {
        inl[r * 66 + 0] = 0.f;
        inl[r * 66 + 65] = 0.f;
    }
    for (int e = threadIdx.x; e < 34 * 64; e += 256) {
        int row = e >> 6, w = e & 63;
        int h = h0 - 1 + row;
        inl[row * 66 + 1 + w] = (h >= 0 && h < 64) ? src[h * 64 + w] : 0.f;
    }
    __syncthreads();
    float wgt[9];
#pragma unroll
    for (int t = 0; t < 9; t++) wgt[t] = cwf[d * 9 + t];
    float bias = cbf[d];
    int hs = threadIdx.x >> 6, w = threadIdx.x & 63;
    float* dstrow = xc + (size_t)(b * Dd + d) * Lc;
#pragma unroll
    for (int it = 0; it < 8; ++it) {
        int hh = it * 4 + hs;
        float acc = bias;
#pragma unroll
        for (int dy = 0; dy < 3; ++dy) {
            const float* rp = &inl[(hh + dy) * 66 + w];
#pragma unroll
            for (int dx = 0; dx < 3; ++dx)
                acc += rp[dx] * wgt[dy * 3 + dx];
        }
        float s = acc / (1.f + __expf(-acc));
        dstrow[(h0 + hh) * 64 + w] = s;
        outl[hh * 65 + w] = s;
    }
    __syncthreads();
    float* udst = uT + (size_t)(b * Dd + d) * Lc;
    for (int e = threadIdx.x; e < 2048; e += 256) {
        int w2 = e >> 5, hh2 = e & 31;
        udst[w2 * 64 + h0 + hh2] = outl[hh2 * 65 + w2];
    }
}

// -------- K3: per-direction projection + dt-proj + softplus --------
// Block = 64 positions x 4 wave-uniform output groups (10 channels each).
// W read via scalar loads (uniform address); x read coalesced from xc/uT.
__global__ __launch_bounds__(256) void k3_proj(const float* __restrict__ xc,
                                               const float* __restrict__ uT,
                                               const float* __restrict__ Wg,
                                               const float* __restrict__ dtwf,
                                               const float* __restrict__ dtbf,
                                               __half* __restrict__ dtH,
                                               float* __restrict__ BsT, float* __restrict__ CsT)
{
    __shared__ float rawdt[6][64];
    int bid = blockIdx.x;            // 512 = 64 tiles x 4 k x 2 b
    int pt = bid & 63, k = (bid >> 6) & 3, b = bid >> 8;
    int s0 = pt * 64;
    int pi = threadIdx.x & 63;
    int q  = __builtin_amdgcn_readfirstlane(threadIdx.x >> 6);   // wave-uniform

    const float* xb = ((k & 1) ? uT : xc) + (size_t)b * Dd * Lc + s0 + pi;
    const float* wk = Wg + (size_t)k * 192 * 40 + q * 10;

    float acc[10];
#pragma unroll
    for (int j = 0; j < 10; ++j) acc[j] = 0.f;

    for (int d = 0; d < 192; ++d) {
        float xv = xb[(size_t)d * Lc];          // coalesced 64-lane read
        const float* wrow = wk + d * 40;        // uniform -> s_load
#pragma unroll
        for (int j = 0; j < 10; ++j) acc[j] += wrow[j] * xv;
    }

    if (q == 0) {
#pragma unroll
        for (int j = 0; j < 6; ++j) rawdt[j][pi] = acc[j];
    }
    // B/C outputs (transposed [n][t] layout), coalesced per row
    size_t bk16 = (size_t)(b * Kk + k) * 16;
#pragma unroll
    for (int j = 0; j < 10; ++j) {
        int cp = q * 10 + j;
        if (cp >= 6 && cp < 22)
            BsT[(bk16 + (cp - 6)) * Lc + s0 + pi] = acc[j];
        else if (cp >= 22 && cp < 38)
            CsT[(bk16 + (cp - 22)) * Lc + s0 + pi] = acc[j];
    }
    __syncthreads();

    // dt projection + softplus: each wave handles 48 d rows
    float raws[6];
#pragma unroll
    for (int r = 0; r < 6; ++r) raws[r] = rawdt[r][pi];
    const float* dtw = dtwf + (size_t)(k * 192 + q * 48) * 6;    // uniform
    const float* dtb = dtbf + k * 192 + q * 48;                  // uniform
    __half* dto = dtH + ((size_t)(b * Kk + k) * Dd + q * 48) * Lc + s0 + pi;
    for (int dd = 0; dd < 48; ++dd) {
        float s = dtb[dd];
#pragma unroll
        for (int r = 0; r < 6; ++r) s += raws[r] * dtw[dd * 6 + r];
        float sp = fmaxf(s, 0.f) + log1pf(__expf(-fabsf(s)));
        dto[(size_t)dd * Lc] = __float2half(sp);
    }
}

// ---------------- KSCAN: chunked selective scan, LDS-staged double buffer ----------------
template<int REV, int PASS3>
__device__ __forceinline__ void scan_run(const float* __restrict__ ubase,
                                         const __half* __restrict__ dbase,
                                         const float* __restrict__ Bbase,
                                         const float* __restrict__ Cbase,
                                         float* u0, float* u1, float* b0, float* b1,
                                         float* c0, float* c1, __half* e0, __half* e1,
                                         int sd, int sc, int dl, int n, int c,
                                         float An, float Dsv,
                                         float* __restrict__ P, float* __restrict__ S,
                                         size_t pidx, __half* __restrict__ yrow)
{
    const int t0 = c * 128;
    const int tg0 = REV ? (Lc - 64 - t0) : t0;
    const int tg1 = REV ? (Lc - 128 - t0) : (t0 + 64);

    float h = PASS3 ? P[pidx] : 0.f;
    float sdt = 0.f, ystash = 0.f;

    // ---- stage tile 0 ----
    float4 ru = *reinterpret_cast<const float4*>(ubase + tg0 + sc);
    float4 rb = *reinterpret_cast<const float4*>(Bbase + tg0 + sc);
    float4 rc{};
    if (PASS3) rc = *reinterpret_cast<const float4*>(Cbase + tg0 + sc);
    uint2 rd = *reinterpret_cast<const uint2*>(dbase + tg0 + sc);
    *reinterpret_cast<float4*>(u0 + sd * 68 + sc) = ru;
    *reinterpret_cast<float4*>(b0 + sd * 68 + sc) = rb;
    if (PASS3) *reinterpret_cast<float4*>(c0 + sd * 68 + sc) = rc;
    *reinterpret_cast<uint2*>(e0 + sd * 68 + sc) = rd;
    __syncthreads();

    // ---- issue tile 1 loads (overlap with compute of tile 0) ----
    ru = *reinterpret_cast<const float4*>(ubase + tg1 + sc);
    rb = *reinterpret_cast<const float4*>(Bbase + tg1 + sc);
    if (PASS3) rc = *reinterpret_cast<const float4*>(Cbase + tg1 + sc);
    rd = *reinterpret_cast<const uint2*>(dbase + tg1 + sc);

#define SS2D_COMPUTE(UU, BB, CC, EE, IBASE)                                     \
    {                                                                           \
        _Pragma("unroll")                                                       \
        for (int qi = 0; qi < 16; ++qi) {                                       \
            const int col4 = REV ? (60 - qi * 4) : (qi * 4);                    \
            float4 uq = *reinterpret_cast<const float4*>(UU + dl * 68 + col4);  \
            float4 bq = *reinterpret_cast<const float4*>(BB + n * 68 + col4);   \
            float4 cq{};                                                        \
            if (PASS3) cq = *reinterpret_cast<const float4*>(CC + n * 68 + col4);\
            uint2 dq = *reinterpret_cast<const uint2*>(EE + dl * 68 + col4);    \
            const __half2* dh2 = reinterpret_cast<const __half2*>(&dq);         \
            _Pragma("unroll")                                                   \
            for (int j = 0; j < 4; ++j) {                                       \
                const int e = REV ? (3 - j) : j;                                \
                float dtv = (e & 1) ? __high2float(dh2[e >> 1])                 \
                                    : __low2float(dh2[e >> 1]);                 \
                float uv = reinterpret_cast<const float*>(&uq)[e];              \
                float bv = reinterpret_cast<const float*>(&bq)[e];              \
                float a = __expf(dtv * An);                                     \
                if (!PASS3) sdt += dtv;                                         \
                h = a * h + (dtv * uv) * bv;                                    \
                if (PASS3) {                                                    \
                    float cv = reinterpret_cast<const float*>(&cq)[e];          \
                    float yv = red16(h * cv);                                   \
                    const int i15 = (qi & 3) * 4 + j;                           \
                    if (i15 == n) ystash = yv + uv * Dsv;                       \
                    if (i15 == 15) {                                            \
                        int tb = t0 + (IBASE) + (qi & ~3) * 4 + n;              \
                        int aw = REV ? (Lc - 1 - tb) : tb;                      \
                        yrow[aw] = __float2half(ystash);                        \
                    }                                                           \
                }                                                               \
            }                                                                   \
        }                                                                       \
    }

    SS2D_COMPUTE(u0, b0, c0, e0, 0);

    // ---- write tile 1 to LDS (vmcnt wait absorbed here) ----
    *reinterpret_cast<float4*>(u1 + sd * 68 + sc) = ru;
    *reinterpret_cast<float4*>(b1 + sd * 68 + sc) = rb;
    if (PASS3) *reinterpret_cast<float4*>(c1 + sd * 68 + sc) = rc;
    *reinterpret_cast<uint2*>(e1 + sd * 68 + sc) = rd;
    __syncthreads();

    SS2D_COMPUTE(u1, b1, c1, e1, 64);
#undef SS2D_COMPUTE

    if (!PASS3) {
        P[pidx] = __expf(An * sdt);
        S[pidx] = h;
    }
}

template<int PASS3>
__global__ __launch_bounds__(256) void kscan(const __half* __restrict__ dtH,
                                             const float* __restrict__ xc,
                                             const float* __restrict__ uT,
                                             const float* __restrict__ BsT,
                                             const float* __restrict__ CsT,
                                             const float* __restrict__ alogf,
                                             const float* __restrict__ dsf,
                                             float* __restrict__ P,
                                             float* __restrict__ S,
                                             __half* __restrict__ ysH)
{
    __shared__ float uL[2][16 * 68];
    __shared__ float bL[2][16 * 68];
    __shared__ float cL[2][PASS3 ? 16 * 68 : 4];
    __shared__ __half dL[2][16 * 68];

    int c  = blockIdx.x & 31;
    int t1 = blockIdx.x >> 5;          // 0..95
    int dg = t1 % 12;
    int kk = (t1 / 12) & 3;
    int b  = t1 / 48;
    int n  = threadIdx.x & 15, dl = threadIdx.x >> 4;
    int d  = dg * 16 + dl;

    int sd = dl;          // staging row (d-row for u/dt, n-row for B/C)
    int sc = n * 4;       // staging col (floats/halfs)

    const float* ubz = ((kk & 1) ? uT : xc) + (size_t)b * Dd * Lc;
    const float*  ubase = ubz + (size_t)(dg * 16 + sd) * Lc;
    const __half* dbase = dtH + ((size_t)((b * Kk + kk) * Dd + dg * 16 + sd)) * Lc;
    const float*  Bbase = BsT + ((size_t)((b * Kk + kk) * 16 + sd)) * Lc;
    const float*  Cbase = CsT + ((size_t)((b * Kk + kk) * 16 + sd)) * Lc;

    float An  = -__expf(alogf[(kk * Dd + d) * 16 + n]);
    float Dsv = PASS3 ? dsf[kk * Dd + d] : 0.f;
    size_t pidx = (((size_t)(b * Kk + kk) * Dd + d) * NC + c) * 16 + n;
    __half* yrow = PASS3 ? ysH + ((size_t)(kk * Bsz + b) * Dd + d) * Lc : nullptr;

    if (kk >= 2)
        scan_run<1, PASS3>(ubase, dbase, Bbase, Cbase,
                           uL[0], uL[1], bL[0], bL[1], cL[0], cL[1], dL[0], dL[1],
                           sd, sc, dl, n, c, An, Dsv, P, S, pidx, yrow);
    else
        scan_run<0, PASS3>(ubase, dbase, Bbase, Cbase,
                           uL[0], uL[1], bL[0], bL[1], cL[0], cL[1], dL[0], dL[1],
                           sd, sc, dl, n, c, An, Dsv, P, S, pidx, yrow);
}

// ---------------- K6: chunk-level scan; carry-in written in place over P ----------------
__global__ __launch_bounds__(256) void k6_pass2(float* __restrict__ P, const float* __restrict__ S)
{
    int g = blockIdx.x * 256 + threadIdx.x;   // 24576
    int n = g & 15;
    int chain = g >> 4;
    size_t base = (size_t)chain * NC * 16 + n;
    float h = 0.f;
    for (int c = 0; c < NC; ++c) {
        size_t id = base + (size_t)c * 16;
        float p = P[id], s = S[id];
        P[id] = h;
        h = p * h + s;
    }
}

// ---------------- K8t: ysT = transpose(ys1 + ys3) per (b,d) ----------------
__global__ __launch_bounds__(256) void k8t(const __half* __restrict__ ysH,
                                           __half* __restrict__ ysT)
{
    __shared__ float t[64 * 65];
    int bid = blockIdx.x;
    int d = bid % Dd, b = bid / Dd;
    const __half* y1 = ysH + ((size_t)(1 * Bsz + b) * Dd + d) * Lc;
    const __half* y3 = ysH + ((size_t)(3 * Bsz + b) * Dd + d) * Lc;
    __half* dst = ysT + ((size_t)b * Dd + d) * Lc;
    for (int e = threadIdx.x; e < 4096; e += 256)
        t[(e >> 6) * 65 + (e & 63)] = __half2float(y1[e]) + __half2float(y3[e]);
    __syncthreads();
    for (int e = threadIdx.x; e < 4096; e += 256)
        dst[e] = __float2half(t[(e & 63) * 65 + (e >> 6)]);
}

// ---------------- K8: merge + LayerNorm + SiLU(z) gate -> gH ----------------
__global__ __launch_bounds__(256) void k8_norm(const __half* __restrict__ ysH,
                                               const __half* __restrict__ ysT,
                                               const __half* __restrict__ zsH,
                                               const float* __restrict__ nwf,
                                               const float* __restrict__ nbf,
                                               __half* __restrict__ gH)
{
    __shared__ float yt[192 * 33];
    __shared__ float ps1[8 * 32], ps2[8 * 32];
    __shared__ float mu[32], rs[32];
    int bid = blockIdx.x;
    int pt = bid & 127, b = bid >> 7;
    int p0 = pt * 32;
    for (int e = threadIdx.x; e < 192 * 32; e += 256) {
        int d = e >> 5, p = e & 31;
        size_t r0 = ((size_t)(0 * Bsz + b) * Dd + d) * Lc + p0 + p;
        size_t r2 = ((size_t)(2 * Bsz + b) * Dd + d) * Lc + p0 + p;
        size_t rt = ((size_t)b * Dd + d) * Lc + p0 + p;
        yt[d * 33 + p] = __half2float(ysH[r0]) + __half2float(ysH[r2]) + __half2float(ysT[rt]);
    }
    __syncthreads();
    {
        int p = threadIdx.x & 31, q = threadIdx.x >> 5;
        float s1 = 0.f, s2 = 0.f;
        for (int dd = 0; dd < 24; ++dd) {
            float v = yt[(q * 24 + dd) * 33 + p];
            s1 += v; s2 += v * v;
        }
        ps1[q * 32 + p] = s1; ps2[q * 32 + p] = s2;
    }
    __syncthreads();
    if (threadIdx.x < 32) {
        int p = threadIdx.x;
        float s1 = 0.f, s2 = 0.f;
        for (int q = 0; q < 8; ++q) { s1 += ps1[q * 32 + p]; s2 += ps2[q * 32 + p]; }
        float m = s1 * (1.f / 192.f);
        float var = s2 * (1.f / 192.f) - m * m;
        mu[p] = m; rs[p] = rsqrtf(var + 1e-5f);
    }
    __syncthreads();
    for (int i = threadIdx.x; i < 32 * 192; i += 256) {
        int p = i / 192, d = i - p * 192;
        float v = (yt[d * 33 + p] - mu[p]) * rs[p] * nwf[d] + nbf[d];
        size_t addr = ((size_t)b * Lc + p0 + p) * Dd + d;
        float zv = __half2float(zsH[addr]);
        gH[addr] = __float2half(v * zv);
    }
}

// ---------------- K10: out_proj GEMM (8192 x 96 x 192) ----------------
__global__ __launch_bounds__(256) void k10_outproj(const __half* __restrict__ gH,
                                                   const float* __restrict__ wof,
                                                   const int* __restrict__ flag,
                                                   void* __restrict__ outv)
{
    __shared__ float wT[192 * 100];   // [d][c], padded
    const int bf = flag[0];
    for (int e = threadIdx.x; e < 96 * 192; e += 256) {
        int cI = e / 192, dI = e - cI * 192;
        wT[dI * 100 + cI] = wof[e];
    }
    __syncthreads();
    int r0 = blockIdx.x * 32;
    int r = threadIdx.x >> 3, cg = threadIdx.x & 7;
    const __half* grow = gH + (size_t)(r0 + r) * Dd;
    float acc[12];
#pragma unroll
    for (int i = 0; i < 12; ++i) acc[i] = 0.f;
    for (int d0 = 0; d0 < 192; d0 += 8) {
        __half2 g2[4];
        *reinterpret_cast<uint4*>(g2) = *reinterpret_cast<const uint4*>(grow + d0);
#pragma unroll
        for (int j = 0; j < 8; ++j) {
            float gf = (j & 1) ? __high2float(g2[j >> 1]) : __low2float(g2[j >> 1]);
            const float* wrow = &wT[(d0 + j) * 100 + cg * 12];
            float4 w0 = *reinterpret_cast<const float4*>(wrow);
            float4 w1 = *reinterpret_cast<const float4*>(wrow + 4);
            float4 w2 = *reinterpret_cast<const float4*>(wrow + 8);
            acc[0] += gf * w0.x; acc[1] += gf * w0.y; acc[2]  += gf * w0.z; acc[3]  += gf * w0.w;
            acc[4] += gf * w1.x; acc[5] += gf * w1.y; acc[6]  += gf * w1.z; acc[7]  += gf * w1.w;
            acc[8] += gf * w2.x; acc[9] += gf * w2.y; acc[10] += gf * w2.z; acc[11] += gf * w2.w;
        }
    }
    size_t obase = (size_t)(r0 + r) * Cc + cg * 12;
    if (bf) {
        unsigned short* o = (unsigned short*)outv;
#pragma unroll
        for (int cc = 0; cc < 12; ++cc) o[obase + cc] = f2b(acc[cc]);
    } else {
        float* o = (float*)outv;
#pragma unroll
        for (int cc = 0; cc < 12; ++cc) o[obase + cc] = acc[cc];
    }
}

extern "C" void kernel_launch(void* const* d_in, const int* in_sizes, int n_in,
                              void* d_out, int out_size, void* d_ws, size_t ws_size,
                              hipStream_t stream)
{
    (void)out_size; (void)ws_size;
    float* ws = (float*)d_ws;
    int* flag = (int*)ws;

    // converted weight region (inputs 1..11), starts at 64, ends < 131072
    int off[12]; int tot = 64;
    off[0] = 0;
    for (int i = 1; i < 12; ++i) {
        off[i] = tot;
        int n = (i < n_in) ? in_sizes[i] : 0;
        tot += (n + 63) & ~63;
    }
    float* winf = ws + off[1];
    float* cwf  = ws + off[2];
    float* cbf  = ws + off[3];
    float* xpwf = ws + off[4];
    float* dtwf = ws + off[5];
    float* dtbf = ws + off[6];
    float* alogf= ws + off[7];
    float* dsf  = ws + off[8];
    float* nwf  = ws + off[9];
    float* nbf  = ws + off[10];
    float* wof  = ws + off[11];

    const size_t BASE = 131072;
    __half* dtH = (__half*)(ws + BASE);            // 6291456 h  (B,K,Di,L)
    float*  xc  = ws + BASE + 3145728;             // 1572864 f  (B,Di,L)
    float*  uT  = ws + BASE + 4718592;             // 1572864 f  (B,Di,L) col-major
    float*  BsT = ws + BASE + 6291456;             // 524288 f   (B,K,N,L)
    float*  CsT = ws + BASE + 6815744;             // 524288 f
    float*  P   = ws + BASE + 7340032;             // 786432 f   ; alias ysT after pass3
    float*  S   = ws + BASE + 8126464;             // 786432 f   ; alias gH after k6
    __half* zsH = (__half*)(ws + BASE + 8912896);  // 1572864 h  (B,L,Di)
    float*  xi  = ws + BASE + 9699328;             // 1572864 f  (B,L,Di); dead after k2a
    float*  xiT = ws + BASE + 9699328 + 1572864;   // 1572864 f  (B,Di,L); dead after k2b
    __half* ysH = (__half*)(ws + BASE + 9699328);  // 6291456 h  (K,B,Di,L) — overlays xi/xiT
    __half* ysT = (__half*)P;                      // 1572864 h  (B,Di,L)
    __half* gH  = (__half*)S;                      // 1572864 h  (B,L,Di)
    float*  Wg  = ws + BASE + 12845056;            // 30720 f    (K,Di,40) padded W
    // end = BASE + 12875776 floats = 52.1 MB

    Cv cv;
    for (int i = 0; i < 11; ++i) {
        int t = i + 1;
        cv.src[i] = (t < n_in) ? d_in[t] : d_in[0];
        cv.off[i] = off[t];
        cv.n[i]   = (t < n_in) ? in_sizes[t] : 0;
    }

    k0_detect   <<<dim3(1),    dim3(256), 0, stream>>>((const unsigned short*)d_in[0], flag);
    k0b_convert <<<dim3(144, 11), dim3(256), 0, stream>>>(cv, flag, ws);
    k3w_prep    <<<dim3(120),  dim3(256), 0, stream>>>(xpwf, Wg);
    k1_inproj   <<<dim3(1024), dim3(256), 0, stream>>>(d_in[0], flag, winf, xi, zsH);
    k2a_transpose<<<dim3(384), dim3(256), 0, stream>>>(xi, xiT);
    k2b_conv    <<<dim3(768),  dim3(256), 0, stream>>>(xiT, cwf, cbf, xc, uT);
    k3_proj     <<<dim3(512),  dim3(256), 0, stream>>>(xc, uT, Wg, dtwf, dtbf, dtH, BsT, CsT);
    kscan<0>    <<<dim3(3072), dim3(256), 0, stream>>>(dtH, xc, uT, BsT, CsT, alogf, dsf, P, S, ysH);
    k6_pass2    <<<dim3(96),   dim3(256), 0, stream>>>(P, S);
    kscan<1>    <<<dim3(3072), dim3(256), 0, stream>>>(dtH, xc, uT, BsT, CsT, alogf, dsf, P, S, ysH);
    k8t         <<<dim3(384),  dim3(256), 0, stream>>>(ysH, ysT);
    k8_norm     <<<dim3(256),  dim3(256), 0, stream>>>(ysH, ysT, zsH, nwf, nbf, gH);
    k10_outproj <<<dim3(256),  dim3(256), 0, stream>>>(gH, wof, flag, d_out);
}

// Round 9
// 200.809 us; speedup vs baseline: 2.0542x; 1.1060x over previous
//
#include <hip/hip_runtime.h>
#include <hip/hip_fp16.h>
#include <math.h>

// SS2D fused block. B=2, H=W=64, L=4096, C=96, Di=192, K=4, N=16, R=6.
// Input dtype (bf16 vs f32) detected at runtime; internal compute f32 (dt/z/ys f16).
// Workspace: ~52.1 MB.

static constexpr int Bsz = 2;
static constexpr int Lc  = 4096;
static constexpr int Cc  = 96;
static constexpr int Dd  = 192;
static constexpr int Kk  = 4;
static constexpr int NC  = 32;     // chunks of 128 steps

__device__ __forceinline__ float bu(unsigned short v) {
    return __uint_as_float((unsigned int)v << 16);
}
__device__ __forceinline__ unsigned short f2b(float f) {
    unsigned int u = __float_as_uint(f);
    return (unsigned short)((u + 0x7fffu + ((u >> 16) & 1u)) >> 16);
}

// DPP 16-lane row reduction: 4 full-rate VALU adds, no DS pipe.
template<int CTRL>
__device__ __forceinline__ float dppadd(float x) {
    return x + __int_as_float(__builtin_amdgcn_update_dpp(
        0, __float_as_int(x), CTRL, 0xf, 0xf, true));
}
__device__ __forceinline__ float red16(float x) {
    x = dppadd<0xB1>(x);    // quad_perm [1,0,3,2]  (xor 1)
    x = dppadd<0x4E>(x);    // quad_perm [2,3,0,1]  (xor 2)
    x = dppadd<0x124>(x);   // row_ror:4
    x = dppadd<0x128>(x);   // row_ror:8
    return x;
}

// ---------------- K0: dtype detector (bf16 vs f32) ----------------
__global__ __launch_bounds__(256) void k0_detect(const unsigned short* __restrict__ x,
                                                 int* __restrict__ flag)
{
    __shared__ int s[256];
    int cnt = 0;
    for (int i = threadIdx.x; i < 4096; i += 256) {
        int e = (x[i] >> 7) & 0xFF;
        cnt += (e >= 118 && e <= 131) ? 1 : 0;
    }
    s[threadIdx.x] = cnt;
    __syncthreads();
    for (int st = 128; st > 0; st >>= 1) {
        if (threadIdx.x < st) s[threadIdx.x] += s[threadIdx.x + st];
        __syncthreads();
    }
    if (threadIdx.x == 0) flag[0] = (s[0] >= 3072) ? 1 : 0;
}

// ---------------- K0b: convert weight inputs (1..11) to canonical f32 ----------------
struct Cv {
    const void* src[11];
    int off[11];
    int n[11];
};
__global__ __launch_bounds__(256) void k0b_convert(Cv cv, const int* __restrict__ flag,
                                                   float* __restrict__ dstbase)
{
    int bf = flag[0];
    int t = blockIdx.y;
    int i = blockIdx.x * 256 + threadIdx.x;
    if (i >= cv.n[t]) return;
    float v;
    if (bf) v = bu(((const unsigned short*)cv.src[t])[i]);
    else    v = ((const float*)cv.src[t])[i];
    dstbase[cv.off[t] + i] = v;
}

// ---------------- K3w: build Wg[k][d][40] = x_proj_weight[k][cp][d] (pad->0) ----------------
__global__ __launch_bounds__(256) void k3w_prep(const float* __restrict__ xpwf,
                                                float* __restrict__ Wg)
{
    int idx = blockIdx.x * 256 + threadIdx.x;   // 30720 total
    if (idx >= 4 * 192 * 40) return;
    int cp = idx % 40;
    int d  = (idx / 40) % 192;
    int k  = idx / 7680;
    Wg[idx] = (cp < 38) ? xpwf[(size_t)(k * 38 + cp) * 192 + d] : 0.f;
}

// ---------------- K1: in_proj GEMM (8192x384x96), split xi / silu(z) ----------------
__global__ __launch_bounds__(256) void k1_inproj(const void* __restrict__ xraw,
                                                 const int* __restrict__ flag,
                                                 const float* __restrict__ wf,
                                                 float* __restrict__ xi, __half* __restrict__ zs)
{
    __shared__ float xT[32 * 97];
    __shared__ float wT[96 * 97];
    const int bf = flag[0];
    int tile = blockIdx.x >> 2, jq = blockIdx.x & 3;
    int b = tile >> 7;
    int l0 = (tile & 127) << 5;
    int j0 = jq * 96;
    for (int e = threadIdx.x; e < 32 * 96; e += 256) {
        int i = e / 96, c = e % 96;
        size_t idx = (size_t)(b * Lc + l0 + i) * Cc + c;
        xT[i * 97 + c] = bf ? bu(((const unsigned short*)xraw)[idx])
                            : ((const float*)xraw)[idx];
    }
    for (int e = threadIdx.x; e < 96 * 96; e += 256) {
        int j = e / 96, c = e % 96;
        wT[j * 97 + c] = wf[(size_t)(j0 + j) * Cc + c];
    }
    __syncthreads();
    int jj = threadIdx.x & 31, ll = threadIdx.x >> 5;
    float acc[4][3];
#pragma unroll
    for (int i = 0; i < 4; i++)
#pragma unroll
        for (int m = 0; m < 3; m++) acc[i][m] = 0.f;
    for (int c = 0; c < 96; ++c) {
        float xv[4], wv[3];
#pragma unroll
        for (int i = 0; i < 4; i++) xv[i] = xT[(ll * 4 + i) * 97 + c];
#pragma unroll
        for (int m = 0; m < 3; m++) wv[m] = wT[(jj + 32 * m) * 97 + c];
#pragma unroll
        for (int i = 0; i < 4; i++)
#pragma unroll
            for (int m = 0; m < 3; m++) acc[i][m] += xv[i] * wv[m];
    }
#pragma unroll
    for (int i = 0; i < 4; i++) {
        int l = l0 + ll * 4 + i;
#pragma unroll
        for (int m = 0; m < 3; m++) {
            int j = j0 + jj + 32 * m;
            float v = acc[i][m];
            if (j < Dd) xi[(size_t)(b * Lc + l) * Dd + j] = v;
            else        zs[(size_t)(b * Lc + l) * Dd + (j - Dd)] = __float2half(v / (1.f + __expf(-v)));
        }
    }
}

// ---------------- K2a: transpose xi (B,L,Di) -> xiT (B,Di,L) ----------------
__global__ __launch_bounds__(256) void k2a_transpose(const float* __restrict__ xi,
                                                     float* __restrict__ xiT)
{
    __shared__ float t[64 * 65];
    int bid = blockIdx.x;
    int lq = bid & 63, dq = (bid >> 6) % 3, b = bid / 192;
    int l0 = lq * 64, d0 = dq * 64;
    for (int e = threadIdx.x; e < 4096; e += 256) {
        int i = e >> 6, j = e & 63;
        t[i * 65 + j] = xi[(size_t)(b * Lc + l0 + i) * Dd + d0 + j];
    }
    __syncthreads();
    for (int e = threadIdx.x; e < 4096; e += 256) {
        int j = e >> 6, i = e & 63;
        xiT[(size_t)(b * Dd + d0 + j) * Lc + l0 + i] = t[i * 65 + j];
    }
}

// -------- K2b: depthwise 3x3 conv + bias + SiLU (channel-first), writes xc and uT --------
__global__ __launch_bounds__(256) void k2b_conv(const float* __restrict__ xiT,
                                                const float* __restrict__ cwf,
                                                const float* __restrict__ cbf,
                                                float* __restrict__ xc,
                                                float* __restrict__ uT)
{
    __shared__ float inl[34 * 66];   // rows h0-1..h0+32, cols zero-padded
    __shared__ float outl[32 * 65];
    int bid = blockIdx.x;
    int half = bid & 1;
    int d = (bid >> 1) % Dd;
    int b = bid / (2 * Dd);
    int h0 = half * 32;
    const float* src = xiT + (size_t)(b * Dd + d) * Lc;
    for (int r = threadIdx.x; r < 34; r += 256) {
        inl[r * 66 + 0] = 0.f;
        inl[r * 66 + 65] = 0.f;
    }
    for (int e = threadIdx.x; e < 34 * 64; e += 256) {
        int row = e >> 6, w = e & 63;
        int h = h0 - 1 + row;
        inl[row * 66 + 1 + w] = (h >= 0 && h < 64) ? src[h * 64 + w] : 0.f;
    }
    __syncthreads();
    float wgt[9];
#pragma unroll
    for (int t = 0; t < 9; t++) wgt[t] = cwf[d * 9 + t];
    float bias = cbf[d];
    int hs = threadIdx.x >> 6, w = threadIdx.x & 63;
    float* dstrow = xc + (size_t)(b * Dd + d) * Lc;
#pragma unroll
    for (int it = 0; it < 8; ++it) {
        int hh = it * 4 + hs;
        float acc = bias;
#pragma unroll
        for (int dy = 0; dy < 3; ++dy) {
            const float* rp = &inl[(hh + dy) * 66 + w];
#pragma unroll
            for (int dx = 0; dx < 3; ++dx)
                acc += rp[dx] * wgt[dy * 3 + dx];
        }
        float s = acc / (1.f + __expf(-acc));
        dstrow[(h0 + hh) * 64 + w] = s;
        outl[hh * 65 + w] = s;
    }
    __syncthreads();
    float* udst = uT + (size_t)(b * Dd + d) * Lc;
    for (int e = threadIdx.x; e < 2048; e += 256) {
        int w2 = e >> 5, hh2 = e & 31;
        udst[w2 * 64 + h0 + hh2] = outl[hh2 * 65 + w2];
    }
}

// -------- K3: per-direction projection + dt-proj + softplus --------
__global__ __launch_bounds__(256) void k3_proj(const float* __restrict__ xc,
                                               const float* __restrict__ uT,
                                               const float* __restrict__ Wg,
                                               const float* __restrict__ dtwf,
                                               const float* __restrict__ dtbf,
                                               __half* __restrict__ dtH,
                                               float* __restrict__ BsT, float* __restrict__ CsT)
{
    __shared__ float rawdt[6][64];
    int bid = blockIdx.x;            // 512 = 64 tiles x 4 k x 2 b
    int pt = bid & 63, k = (bid >> 6) & 3, b = bid >> 8;
    int s0 = pt * 64;
    int pi = threadIdx.x & 63;
    int q  = __builtin_amdgcn_readfirstlane(threadIdx.x >> 6);   // wave-uniform

    const float* xb = ((k & 1) ? uT : xc) + (size_t)b * Dd * Lc + s0 + pi;
    const float* wk = Wg + (size_t)k * 192 * 40 + q * 10;

    float acc[10];
#pragma unroll
    for (int j = 0; j < 10; ++j) acc[j] = 0.f;

    for (int d = 0; d < 192; ++d) {
        float xv = xb[(size_t)d * Lc];          // coalesced 64-lane read
        const float* wrow = wk + d * 40;        // uniform -> s_load
#pragma unroll
        for (int j = 0; j < 10; ++j) acc[j] += wrow[j] * xv;
    }

    if (q == 0) {
#pragma unroll
        for (int j = 0; j < 6; ++j) rawdt[j][pi] = acc[j];
    }
    // B/C outputs (transposed [n][t] layout), coalesced per row
    size_t bk16 = (size_t)(b * Kk + k) * 16;
#pragma unroll
    for (int j = 0; j < 10; ++j) {
        int cp = q * 10 + j;
        if (cp >= 6 && cp < 22)
            BsT[(bk16 + (cp - 6)) * Lc + s0 + pi] = acc[j];
        else if (cp >= 22 && cp < 38)
            CsT[(bk16 + (cp - 22)) * Lc + s0 + pi] = acc[j];
    }
    __syncthreads();

    // dt projection + softplus: each wave handles 48 d rows
    float raws[6];
#pragma unroll
    for (int r = 0; r < 6; ++r) raws[r] = rawdt[r][pi];
    const float* dtw = dtwf + (size_t)(k * 192 + q * 48) * 6;    // uniform
    const float* dtb = dtbf + k * 192 + q * 48;                  // uniform
    __half* dto = dtH + ((size_t)(b * Kk + k) * Dd + q * 48) * Lc + s0 + pi;
    for (int dd = 0; dd < 48; ++dd) {
        float s = dtb[dd];
#pragma unroll
        for (int r = 0; r < 6; ++r) s += raws[r] * dtw[dd * 6 + r];
        float sp = fmaxf(s, 0.f) + log1pf(__expf(-fabsf(s)));
        dto[(size_t)dd * Lc] = __float2half(sp);
    }
}

// ---------------- KSCAN: chunked selective scan, single LDS tile, 1 barrier ----------------
// Block = 16 d-lanes x 16 n-lanes; chunk = 128 steps staged in one LDS tile.
// Row strides 132 f / 136 h -> bank stride 4 -> worst 2-way conflict (free).
template<int REV, int PASS3>
__device__ __forceinline__ void scan_run(const float* __restrict__ ubase,
                                         const __half* __restrict__ dbase,
                                         const float* __restrict__ Bbase,
                                         const float* __restrict__ Cbase,
                                         float* uL, float* bL, float* cL, __half* dL,
                                         int dl, int n, int c,
                                         float An, float Dsv,
                                         float* __restrict__ P, float* __restrict__ S,
                                         size_t pidx, __half* __restrict__ yrow)
{
    const int t0 = c * 128;
    const int tg = REV ? (Lc - 128 - t0) : t0;

    // ---- stage 128 steps (transient registers, die before barrier) ----
    {
        float4 ru0 = *reinterpret_cast<const float4*>(ubase + tg + n * 4);
        float4 ru1 = *reinterpret_cast<const float4*>(ubase + tg + 64 + n * 4);
        float4 rb0 = *reinterpret_cast<const float4*>(Bbase + tg + n * 4);
        float4 rb1 = *reinterpret_cast<const float4*>(Bbase + tg + 64 + n * 4);
        uint4  rd  = *reinterpret_cast<const uint4*>(dbase + tg + n * 8);
        *reinterpret_cast<float4*>(uL + dl * 132 + n * 4) = ru0;
        *reinterpret_cast<float4*>(uL + dl * 132 + 64 + n * 4) = ru1;
        *reinterpret_cast<float4*>(bL + dl * 132 + n * 4) = rb0;
        *reinterpret_cast<float4*>(bL + dl * 132 + 64 + n * 4) = rb1;
        *reinterpret_cast<uint4*>(dL + dl * 136 + n * 8) = rd;
        if (PASS3) {
            float4 rc0 = *reinterpret_cast<const float4*>(Cbase + tg + n * 4);
            float4 rc1 = *reinterpret_cast<const float4*>(Cbase + tg + 64 + n * 4);
            *reinterpret_cast<float4*>(cL + dl * 132 + n * 4) = rc0;
            *reinterpret_cast<float4*>(cL + dl * 132 + 64 + n * 4) = rc1;
        }
    }
    __syncthreads();

    float h = PASS3 ? P[pidx] : 0.f;
    float sdt = 0.f, ystash = 0.f;

#pragma unroll 4
    for (int qi = 0; qi < 32; ++qi) {
        const int col4 = REV ? (124 - qi * 4) : (qi * 4);
        float4 uq = *reinterpret_cast<const float4*>(uL + dl * 132 + col4);
        float4 bq = *reinterpret_cast<const float4*>(bL + n * 132 + col4);
        float4 cq{};
        if (PASS3) cq = *reinterpret_cast<const float4*>(cL + n * 132 + col4);
        uint2 dq = *reinterpret_cast<const uint2*>(dL + dl * 136 + col4);
        const __half2* dh2 = reinterpret_cast<const __half2*>(&dq);
#pragma unroll
        for (int j = 0; j < 4; ++j) {
            const int e = REV ? (3 - j) : j;
            float dtv = (e & 1) ? __high2float(dh2[e >> 1]) : __low2float(dh2[e >> 1]);
            float uv = reinterpret_cast<const float*>(&uq)[e];
            float bv = reinterpret_cast<const float*>(&bq)[e];
            float a = __expf(dtv * An);
            if (!PASS3) sdt += dtv;
            h = a * h + (dtv * uv) * bv;
            if (PASS3) {
                float cv = reinterpret_cast<const float*>(&cq)[e];
                float yv = red16(h * cv);
                const int i15 = (qi & 3) * 4 + j;
                if (i15 == n) ystash = yv + uv * Dsv;
                if (i15 == 15) {
                    int tb = t0 + (qi >> 2) * 16 + n;
                    int aw = REV ? (Lc - 1 - tb) : tb;
                    yrow[aw] = __float2half(ystash);     // 16-lane coalesced
                }
            }
        }
    }

    if (!PASS3) {
        P[pidx] = __expf(An * sdt);
        S[pidx] = h;
    }
}

template<int PASS3>
__global__ __launch_bounds__(256) void kscan(const __half* __restrict__ dtH,
                                             const float* __restrict__ xc,
                                             const float* __restrict__ uT,
                                             const float* __restrict__ BsT,
                                             const float* __restrict__ CsT,
                                             const float* __restrict__ alogf,
                                             const float* __restrict__ dsf,
                                             float* __restrict__ P,
                                             float* __restrict__ S,
                                             __half* __restrict__ ysH)
{
    __shared__ float uL[16 * 132];
    __shared__ float bL[16 * 132];
    __shared__ float cL[PASS3 ? 16 * 132 : 4];
    __shared__ __half dL[16 * 136];

    int c  = blockIdx.x & 31;
    int t1 = blockIdx.x >> 5;          // 0..95
    int dg = t1 % 12;
    int kk = (t1 / 12) & 3;
    int b  = t1 / 48;
    int n  = threadIdx.x & 15, dl = threadIdx.x >> 4;
    int d  = dg * 16 + dl;

    const float* ubz = ((kk & 1) ? uT : xc) + (size_t)b * Dd * Lc;
    const float*  ubase = ubz + (size_t)d * Lc;
    const __half* dbase = dtH + ((size_t)((b * Kk + kk) * Dd + d)) * Lc;
    const float*  Bbase = BsT + ((size_t)((b * Kk + kk) * 16 + dl)) * Lc;
    const float*  Cbase = CsT + ((size_t)((b * Kk + kk) * 16 + dl)) * Lc;

    float An  = -__expf(alogf[(kk * Dd + d) * 16 + n]);
    float Dsv = PASS3 ? dsf[kk * Dd + d] : 0.f;
    size_t pidx = (((size_t)(b * Kk + kk) * Dd + d) * NC + c) * 16 + n;
    __half* yrow = PASS3 ? ysH + ((size_t)(kk * Bsz + b) * Dd + d) * Lc : nullptr;

    if (kk >= 2)
        scan_run<1, PASS3>(ubase, dbase, Bbase, Cbase, uL, bL, cL, dL,
                           dl, n, c, An, Dsv, P, S, pidx, yrow);
    else
        scan_run<0, PASS3>(ubase, dbase, Bbase, Cbase, uL, bL, cL, dL,
                           dl, n, c, An, Dsv, P, S, pidx, yrow);
}

// ---------------- K6: chunk-level scan; carry-in written in place over P ----------------
__global__ __launch_bounds__(256) void k6_pass2(float* __restrict__ P, const float* __restrict__ S)
{
    int g = blockIdx.x * 256 + threadIdx.x;   // 24576
    int n = g & 15;
    int chain = g >> 4;
    size_t base = (size_t)chain * NC * 16 + n;
    float h = 0.f;
    for (int c = 0; c < NC; ++c) {
        size_t id = base + (size_t)c * 16;
        float p = P[id], s = S[id];
        P[id] = h;
        h = p * h + s;
    }
}

// ---------------- K8t: ysT = transpose(ys1 + ys3) per (b,d) ----------------
__global__ __launch_bounds__(256) void k8t(const __half* __restrict__ ysH,
                                           __half* __restrict__ ysT)
{
    __shared__ float t[64 * 65];
    int bid = blockIdx.x;
    int d = bid % Dd, b = bid / Dd;
    const __half* y1 = ysH + ((size_t)(1 * Bsz + b) * Dd + d) * Lc;
    const __half* y3 = ysH + ((size_t)(3 * Bsz + b) * Dd + d) * Lc;
    __half* dst = ysT + ((size_t)b * Dd + d) * Lc;
    for (int e = threadIdx.x; e < 4096; e += 256)
        t[(e >> 6) * 65 + (e & 63)] = __half2float(y1[e]) + __half2float(y3[e]);
    __syncthreads();
    for (int e = threadIdx.x; e < 4096; e += 256)
        dst[e] = __float2half(t[(e & 63) * 65 + (e >> 6)]);
}

// ---------------- K8: merge + LayerNorm + SiLU(z) gate -> gH ----------------
__global__ __launch_bounds__(256) void k8_norm(const __half* __restrict__ ysH,
                                               const __half* __restrict__ ysT,
                                               const __half* __restrict__ zsH,
                                               const float* __restrict__ nwf,
                                               const float* __restrict__ nbf,
                                               __half* __restrict__ gH)
{
    __shared__ float yt[192 * 33];
    __shared__ float ps1[8 * 32], ps2[8 * 32];
    __shared__ float mu[32], rs[32];
    int bid = blockIdx.x;
    int pt = bid & 127, b = bid >> 7;
    int p0 = pt * 32;
    for (int e = threadIdx.x; e < 192 * 32; e += 256) {
        int d = e >> 5, p = e & 31;
        size_t r0 = ((size_t)(0 * Bsz + b) * Dd + d) * Lc + p0 + p;
        size_t r2 = ((size_t)(2 * Bsz + b) * Dd + d) * Lc + p0 + p;
        size_t rt = ((size_t)b * Dd + d) * Lc + p0 + p;
        yt[d * 33 + p] = __half2float(ysH[r0]) + __half2float(ysH[r2]) + __half2float(ysT[rt]);
    }
    __syncthreads();
    {
        int p = threadIdx.x & 31, q = threadIdx.x >> 5;
        float s1 = 0.f, s2 = 0.f;
        for (int dd = 0; dd < 24; ++dd) {
            float v = yt[(q * 24 + dd) * 33 + p];
            s1 += v; s2 += v * v;
        }
        ps1[q * 32 + p] = s1; ps2[q * 32 + p] = s2;
    }
    __syncthreads();
    if (threadIdx.x < 32) {
        int p = threadIdx.x;
        float s1 = 0.f, s2 = 0.f;
        for (int q = 0; q < 8; ++q) { s1 += ps1[q * 32 + p]; s2 += ps2[q * 32 + p]; }
        float m = s1 * (1.f / 192.f);
        float var = s2 * (1.f / 192.f) - m * m;
        mu[p] = m; rs[p] = rsqrtf(var + 1e-5f);
    }
    __syncthreads();
    for (int i = threadIdx.x; i < 32 * 192; i += 256) {
        int p = i / 192, d = i - p * 192;
        float v = (yt[d * 33 + p] - mu[p]) * rs[p] * nwf[d] + nbf[d];
        size_t addr = ((size_t)b * Lc + p0 + p) * Dd + d;
        float zv = __half2float(zsH[addr]);
        gH[addr] = __float2half(v * zv);
    }
}

// ---------------- K10: out_proj GEMM (8192 x 96 x 192) ----------------
__global__ __launch_bounds__(256) void k10_outproj(const __half* __restrict__ gH,
                                                   const float* __restrict__ wof,
                                                   const int* __restrict__ flag,
                                                   void* __restrict__ outv)
{
    __shared__ float wT[192 * 100];   // [d][c], padded
    const int bf = flag[0];
    for (int e = threadIdx.x; e < 96 * 192; e += 256) {
        int cI = e / 192, dI = e - cI * 192;
        wT[dI * 100 + cI] = wof[e];
    }
    __syncthreads();
    int r0 = blockIdx.x * 32;
    int r = threadIdx.x >> 3, cg = threadIdx.x & 7;
    const __half* grow = gH + (size_t)(r0 + r) * Dd;
    float acc[12];
#pragma unroll
    for (int i = 0; i < 12; ++i) acc[i] = 0.f;
    for (int d0 = 0; d0 < 192; d0 += 8) {
        __half2 g2[4];
        *reinterpret_cast<uint4*>(g2) = *reinterpret_cast<const uint4*>(grow + d0);
#pragma unroll
        for (int j = 0; j < 8; ++j) {
            float gf = (j & 1) ? __high2float(g2[j >> 1]) : __low2float(g2[j >> 1]);
            const float* wrow = &wT[(d0 + j) * 100 + cg * 12];
            float4 w0 = *reinterpret_cast<const float4*>(wrow);
            float4 w1 = *reinterpret_cast<const float4*>(wrow + 4);
            float4 w2 = *reinterpret_cast<const float4*>(wrow + 8);
            acc[0] += gf * w0.x; acc[1] += gf * w0.y; acc[2]  += gf * w0.z; acc[3]  += gf * w0.w;
            acc[4] += gf * w1.x; acc[5] += gf * w1.y; acc[6]  += gf * w1.z; acc[7]  += gf * w1.w;
            acc[8] += gf * w2.x; acc[9] += gf * w2.y; acc[10] += gf * w2.z; acc[11] += gf * w2.w;
        }
    }
    size_t obase = (size_t)(r0 + r) * Cc + cg * 12;
    if (bf) {
        unsigned short* o = (unsigned short*)outv;
#pragma unroll
        for (int cc = 0; cc < 12; ++cc) o[obase + cc] = f2b(acc[cc]);
    } else {
        float* o = (float*)outv;
#pragma unroll
        for (int cc = 0; cc < 12; ++cc) o[obase + cc] = acc[cc];
    }
}

extern "C" void kernel_launch(void* const* d_in, const int* in_sizes, int n_in,
                              void* d_out, int out_size, void* d_ws, size_t ws_size,
                              hipStream_t stream)
{
    (void)out_size; (void)ws_size;
    float* ws = (float*)d_ws;
    int* flag = (int*)ws;

    // converted weight region (inputs 1..11), starts at 64, ends < 131072
    int off[12]; int tot = 64;
    off[0] = 0;
    for (int i = 1; i < 12; ++i) {
        off[i] = tot;
        int n = (i < n_in) ? in_sizes[i] : 0;
        tot += (n + 63) & ~63;
    }
    float* winf = ws + off[1];
    float* cwf  = ws + off[2];
    float* cbf  = ws + off[3];
    float* xpwf = ws + off[4];
    float* dtwf = ws + off[5];
    float* dtbf = ws + off[6];
    float* alogf= ws + off[7];
    float* dsf  = ws + off[8];
    float* nwf  = ws + off[9];
    float* nbf  = ws + off[10];
    float* wof  = ws + off[11];

    const size_t BASE = 131072;
    __half* dtH = (__half*)(ws + BASE);            // 6291456 h  (B,K,Di,L)
    float*  xc  = ws + BASE + 3145728;             // 1572864 f  (B,Di,L)
    float*  uT  = ws + BASE + 4718592;             // 1572864 f  (B,Di,L) col-major
    float*  BsT = ws + BASE + 6291456;             // 524288 f   (B,K,N,L)
    float*  CsT = ws + BASE + 6815744;             // 524288 f
    float*  P   = ws + BASE + 7340032;             // 786432 f   ; alias ysT after pass3
    float*  S   = ws + BASE + 8126464;             // 786432 f   ; alias gH after k6
    __half* zsH = (__half*)(ws + BASE + 8912896);  // 1572864 h  (B,L,Di)
    float*  xi  = ws + BASE + 9699328;             // 1572864 f  (B,L,Di); dead after k2a
    float*  xiT = ws + BASE + 9699328 + 1572864;   // 1572864 f  (B,Di,L); dead after k2b
    __half* ysH = (__half*)(ws + BASE + 9699328);  // 6291456 h  (K,B,Di,L) — overlays xi/xiT
    __half* ysT = (__half*)P;                      // 1572864 h  (B,Di,L)
    __half* gH  = (__half*)S;                      // 1572864 h  (B,L,Di)
    float*  Wg  = ws + BASE + 12845056;            // 30720 f    (K,Di,40) padded W
    // end = BASE + 12875776 floats = 52.1 MB

    Cv cv;
    for (int i = 0; i < 11; ++i) {
        int t = i + 1;
        cv.src[i] = (t < n_in) ? d_in[t] : d_in[0];
        cv.off[i] = off[t];
        cv.n[i]   = (t < n_in) ? in_sizes[t] : 0;
    }

    k0_detect   <<<dim3(1),    dim3(256), 0, stream>>>((const unsigned short*)d_in[0], flag);
    k0b_convert <<<dim3(144, 11), dim3(256), 0, stream>>>(cv, flag, ws);
    k3w_prep    <<<dim3(120),  dim3(256), 0, stream>>>(xpwf, Wg);
    k1_inproj   <<<dim3(1024), dim3(256), 0, stream>>>(d_in[0], flag, winf, xi, zsH);
    k2a_transpose<<<dim3(384), dim3(256), 0, stream>>>(xi, xiT);
    k2b_conv    <<<dim3(768),  dim3(256), 0, stream>>>(xiT, cwf, cbf, xc, uT);
    k3_proj     <<<dim3(512),  dim3(256), 0, stream>>>(xc, uT, Wg, dtwf, dtbf, dtH, BsT, CsT);
    kscan<0>    <<<dim3(3072), dim3(256), 0, stream>>>(dtH, xc, uT, BsT, CsT, alogf, dsf, P, S, ysH);
    k6_pass2    <<<dim3(96),   dim3(256), 0, stream>>>(P, S);
    kscan<1>    <<<dim3(3072), dim3(256), 0, stream>>>(dtH, xc, uT, BsT, CsT, alogf, dsf, P, S, ysH);
    k8t         <<<dim3(384),  dim3(256), 0, stream>>>(ysH, ysT);
    k8_norm     <<<dim3(256),  dim3(256), 0, stream>>>(ysH, ysT, zsH, nwf, nbf, gH);
    k10_outproj <<<dim3(256),  dim3(256), 0, stream>>>(gH, wof, flag, d_out);
}

// Round 10
// 196.838 us; speedup vs baseline: 2.0957x; 1.0202x over previous
//
#include <hip/hip_runtime.h>
#include <hip/hip_fp16.h>
#include <math.h>

// SS2D fused block. B=2, H=W=64, L=4096, C=96, Di=192, K=4, N=16, R=6.
// Input dtype (bf16 vs f32) detected at runtime; internal compute f32 (dt/z/ys f16).
// Workspace: ~52.1 MB.

static constexpr int Bsz = 2;
static constexpr int Lc  = 4096;
static constexpr int Cc  = 96;
static constexpr int Dd  = 192;
static constexpr int Kk  = 4;
static constexpr int NC  = 32;     // chunks of 128 steps

__device__ __forceinline__ float bu(unsigned short v) {
    return __uint_as_float((unsigned int)v << 16);
}
__device__ __forceinline__ unsigned short f2b(float f) {
    unsigned int u = __float_as_uint(f);
    return (unsigned short)((u + 0x7fffu + ((u >> 16) & 1u)) >> 16);
}

// DPP 16-lane row reduction: 4 full-rate VALU adds, no DS pipe.
template<int CTRL>
__device__ __forceinline__ float dppadd(float x) {
    return x + __int_as_float(__builtin_amdgcn_update_dpp(
        0, __float_as_int(x), CTRL, 0xf, 0xf, true));
}
__device__ __forceinline__ float red16(float x) {
    x = dppadd<0xB1>(x);    // quad_perm [1,0,3,2]  (xor 1)
    x = dppadd<0x4E>(x);    // quad_perm [2,3,0,1]  (xor 2)
    x = dppadd<0x124>(x);   // row_ror:4
    x = dppadd<0x128>(x);   // row_ror:8
    return x;
}

// ---------------- K0: dtype detector (bf16 vs f32) ----------------
__global__ __launch_bounds__(256) void k0_detect(const unsigned short* __restrict__ x,
                                                 int* __restrict__ flag)
{
    __shared__ int s[256];
    int cnt = 0;
    for (int i = threadIdx.x; i < 4096; i += 256) {
        int e = (x[i] >> 7) & 0xFF;
        cnt += (e >= 118 && e <= 131) ? 1 : 0;
    }
    s[threadIdx.x] = cnt;
    __syncthreads();
    for (int st = 128; st > 0; st >>= 1) {
        if (threadIdx.x < st) s[threadIdx.x] += s[threadIdx.x + st];
        __syncthreads();
    }
    if (threadIdx.x == 0) flag[0] = (s[0] >= 3072) ? 1 : 0;
}

// ------- K0b: convert weight inputs (1..11) to f32; slot 11 builds Wg -------
struct Cv {
    const void* src[12];
    int off[12];
    int n[12];
};
__global__ __launch_bounds__(256) void k0b_convert(Cv cv, const int* __restrict__ flag,
                                                   float* __restrict__ dstbase)
{
    int bf = flag[0];
    int t = blockIdx.y;
    int i = blockIdx.x * 256 + threadIdx.x;
    if (i >= cv.n[t]) return;
    if (t == 11) {
        // Wg[k][d][40] = x_proj_weight[k][cp][d] (cp>=38 -> 0), from RAW input
        int cp = i % 40;
        int d  = (i / 40) % 192;
        int k  = i / 7680;
        float v = 0.f;
        if (cp < 38) {
            size_t si = (size_t)(k * 38 + cp) * 192 + d;
            v = bf ? bu(((const unsigned short*)cv.src[11])[si])
                   : ((const float*)cv.src[11])[si];
        }
        dstbase[cv.off[11] + i] = v;
        return;
    }
    float v;
    if (bf) v = bu(((const unsigned short*)cv.src[t])[i]);
    else    v = ((const float*)cv.src[t])[i];
    dstbase[cv.off[t] + i] = v;
}

// -------- K1: in_proj GEMM (8192x384x96) -> xiT (B,Di,L) f32, zT (B,Di,L) f16 --------
// Block = 64 rows x 4 wave-uniform j-groups (24 j each). W via scalar loads.
__global__ __launch_bounds__(256) void k1_inproj(const void* __restrict__ xraw,
                                                 const int* __restrict__ flag,
                                                 const float* __restrict__ wf,
                                                 float* __restrict__ xiT, __half* __restrict__ zT)
{
    __shared__ float xT[64 * 97];
    const int bf = flag[0];
    int lt = blockIdx.x & 127;          // 128 tiles of 64 rows over B*L
    int jq = blockIdx.x >> 7;           // 0..3
    int row0 = lt * 64;
    for (int e = threadIdx.x; e < 64 * 96; e += 256) {
        int i = e / 96, c = e % 96;
        size_t idx = (size_t)(row0 + i) * Cc + c;
        xT[i * 97 + c] = bf ? bu(((const unsigned short*)xraw)[idx])
                            : ((const float*)xraw)[idx];
    }
    __syncthreads();
    int pi = threadIdx.x & 63;
    int q  = __builtin_amdgcn_readfirstlane(threadIdx.x >> 6);
    int j0 = jq * 96 + q * 24;
    float acc[24];
#pragma unroll
    for (int j = 0; j < 24; ++j) acc[j] = 0.f;
    for (int c4 = 0; c4 < 24; ++c4) {
        float xv0 = xT[pi * 97 + c4 * 4 + 0];
        float xv1 = xT[pi * 97 + c4 * 4 + 1];
        float xv2 = xT[pi * 97 + c4 * 4 + 2];
        float xv3 = xT[pi * 97 + c4 * 4 + 3];
#pragma unroll
        for (int j = 0; j < 24; ++j) {
            float4 w4 = *reinterpret_cast<const float4*>(&wf[(size_t)(j0 + j) * 96 + c4 * 4]);
            acc[j] += w4.x * xv0 + w4.y * xv1 + w4.z * xv2 + w4.w * xv3;
        }
    }
    int b = row0 >> 12;
    int l = (row0 & 4095) + pi;
    if (jq < 2) {
#pragma unroll
        for (int j = 0; j < 24; ++j)
            xiT[((size_t)b * Dd + j0 + j) * Lc + l] = acc[j];
    } else {
#pragma unroll
        for (int j = 0; j < 24; ++j) {
            float v = acc[j];
            zT[((size_t)b * Dd + (j0 + j - 192)) * Lc + l] =
                __float2half(v / (1.f + __expf(-v)));
        }
    }
}

// -------- K2b: depthwise 3x3 conv + bias + SiLU (channel-first), writes xc and uT --------
__global__ __launch_bounds__(256) void k2b_conv(const float* __restrict__ xiT,
                                                const float* __restrict__ cwf,
                                                const float* __restrict__ cbf,
                                                float* __restrict__ xc,
                                                float* __restrict__ uT)
{
    __shared__ float inl[34 * 66];   // rows h0-1..h0+32, cols zero-padded
    __shared__ float outl[32 * 65];
    int bid = blockIdx.x;
    int half = bid & 1;
    int d = (bid >> 1) % Dd;
    int b = bid / (2 * Dd);
    int h0 = half * 32;
    const float* src = xiT + (size_t)(b * Dd + d) * Lc;
    for (int r = threadIdx.x; r < 34; r += 256) {
        inl[r * 66 + 0] = 0.f;
        inl[r * 66 + 65] = 0.f;
    }
    for (int e = threadIdx.x; e < 34 * 64; e += 256) {
        int row = e >> 6, w = e & 63;
        int h = h0 - 1 + row;
        inl[row * 66 + 1 + w] = (h >= 0 && h < 64) ? src[h * 64 + w] : 0.f;
    }
    __syncthreads();
    float wgt[9];
#pragma unroll
    for (int t = 0; t < 9; t++) wgt[t] = cwf[d * 9 + t];
    float bias = cbf[d];
    int hs = threadIdx.x >> 6, w = threadIdx.x & 63;
    float* dstrow = xc + (size_t)(b * Dd + d) * Lc;
#pragma unroll
    for (int it = 0; it < 8; ++it) {
        int hh = it * 4 + hs;
        float acc = bias;
#pragma unroll
        for (int dy = 0; dy < 3; ++dy) {
            const float* rp = &inl[(hh + dy) * 66 + w];
#pragma unroll
            for (int dx = 0; dx < 3; ++dx)
                acc += rp[dx] * wgt[dy * 3 + dx];
        }
        float s = acc / (1.f + __expf(-acc));
        dstrow[(h0 + hh) * 64 + w] = s;
        outl[hh * 65 + w] = s;
    }
    __syncthreads();
    float* udst = uT + (size_t)(b * Dd + d) * Lc;
    for (int e = threadIdx.x; e < 2048; e += 256) {
        int w2 = e >> 5, hh2 = e & 31;
        udst[w2 * 64 + h0 + hh2] = outl[hh2 * 65 + w2];
    }
}

// -------- K3: per-direction projection + dt-proj + softplus --------
__global__ __launch_bounds__(256) void k3_proj(const float* __restrict__ xc,
                                               const float* __restrict__ uT,
                                               const float* __restrict__ Wg,
                                               const float* __restrict__ dtwf,
                                               const float* __restrict__ dtbf,
                                               __half* __restrict__ dtH,
                                               float* __restrict__ BsT, float* __restrict__ CsT)
{
    __shared__ float rawdt[6][64];
    int bid = blockIdx.x;            // 512 = 64 tiles x 4 k x 2 b
    int pt = bid & 63, k = (bid >> 6) & 3, b = bid >> 8;
    int s0 = pt * 64;
    int pi = threadIdx.x & 63;
    int q  = __builtin_amdgcn_readfirstlane(threadIdx.x >> 6);   // wave-uniform

    const float* xb = ((k & 1) ? uT : xc) + (size_t)b * Dd * Lc + s0 + pi;
    const float* wk = Wg + (size_t)k * 192 * 40 + q * 10;

    float acc[10];
#pragma unroll
    for (int j = 0; j < 10; ++j) acc[j] = 0.f;

    for (int d = 0; d < 192; ++d) {
        float xv = xb[(size_t)d * Lc];          // coalesced 64-lane read
        const float* wrow = wk + d * 40;        // uniform -> s_load
#pragma unroll
        for (int j = 0; j < 10; ++j) acc[j] += wrow[j] * xv;
    }

    if (q == 0) {
#pragma unroll
        for (int j = 0; j < 6; ++j) rawdt[j][pi] = acc[j];
    }
    size_t bk16 = (size_t)(b * Kk + k) * 16;
#pragma unroll
    for (int j = 0; j < 10; ++j) {
        int cp = q * 10 + j;
        if (cp >= 6 && cp < 22)
            BsT[(bk16 + (cp - 6)) * Lc + s0 + pi] = acc[j];
        else if (cp >= 22 && cp < 38)
            CsT[(bk16 + (cp - 22)) * Lc + s0 + pi] = acc[j];
    }
    __syncthreads();

    float raws[6];
#pragma unroll
    for (int r = 0; r < 6; ++r) raws[r] = rawdt[r][pi];
    const float* dtw = dtwf + (size_t)(k * 192 + q * 48) * 6;    // uniform
    const float* dtb = dtbf + k * 192 + q * 48;                  // uniform
    __half* dto = dtH + ((size_t)(b * Kk + k) * Dd + q * 48) * Lc + s0 + pi;
    for (int dd = 0; dd < 48; ++dd) {
        float s = dtb[dd];
#pragma unroll
        for (int r = 0; r < 6; ++r) s += raws[r] * dtw[dd * 6 + r];
        float sp = fmaxf(s, 0.f) + log1pf(__expf(-fabsf(s)));
        dto[(size_t)dd * Lc] = __float2half(sp);
    }
}

// ---------------- KSCAN: chunked selective scan, single LDS tile, 1 barrier ----------------
template<int REV, int PASS3>
__device__ __forceinline__ void scan_run(const float* __restrict__ ubase,
                                         const __half* __restrict__ dbase,
                                         const float* __restrict__ Bbase,
                                         const float* __restrict__ Cbase,
                                         float* uL, float* bL, float* cL, __half* dL,
                                         int dl, int n, int c,
                                         float An,
                                         float* __restrict__ P, float* __restrict__ S,
                                         size_t pidx, __half* __restrict__ yrow)
{
    const int t0 = c * 128;
    const int tg = REV ? (Lc - 128 - t0) : t0;

    // ---- stage 128 steps (transient registers, die before barrier) ----
    {
        float4 ru0 = *reinterpret_cast<const float4*>(ubase + tg + n * 4);
        float4 ru1 = *reinterpret_cast<const float4*>(ubase + tg + 64 + n * 4);
        float4 rb0 = *reinterpret_cast<const float4*>(Bbase + tg + n * 4);
        float4 rb1 = *reinterpret_cast<const float4*>(Bbase + tg + 64 + n * 4);
        uint4  rd  = *reinterpret_cast<const uint4*>(dbase + tg + n * 8);
        *reinterpret_cast<float4*>(uL + dl * 132 + n * 4) = ru0;
        *reinterpret_cast<float4*>(uL + dl * 132 + 64 + n * 4) = ru1;
        *reinterpret_cast<float4*>(bL + dl * 132 + n * 4) = rb0;
        *reinterpret_cast<float4*>(bL + dl * 132 + 64 + n * 4) = rb1;
        *reinterpret_cast<uint4*>(dL + dl * 136 + n * 8) = rd;
        if (PASS3) {
            float4 rc0 = *reinterpret_cast<const float4*>(Cbase + tg + n * 4);
            float4 rc1 = *reinterpret_cast<const float4*>(Cbase + tg + 64 + n * 4);
            *reinterpret_cast<float4*>(cL + dl * 132 + n * 4) = rc0;
            *reinterpret_cast<float4*>(cL + dl * 132 + 64 + n * 4) = rc1;
        }
    }
    __syncthreads();

    float h = PASS3 ? P[pidx] : 0.f;
    float sdt = 0.f, ystash = 0.f;

#pragma unroll 4
    for (int qi = 0; qi < 32; ++qi) {
        const int col4 = REV ? (124 - qi * 4) : (qi * 4);
        float4 uq = *reinterpret_cast<const float4*>(uL + dl * 132 + col4);
        float4 bq = *reinterpret_cast<const float4*>(bL + n * 132 + col4);
        float4 cq{};
        if (PASS3) cq = *reinterpret_cast<const float4*>(cL + n * 132 + col4);
        uint2 dq = *reinterpret_cast<const uint2*>(dL + dl * 136 + col4);
        const __half2* dh2 = reinterpret_cast<const __half2*>(&dq);
#pragma unroll
        for (int j = 0; j < 4; ++j) {
            const int e = REV ? (3 - j) : j;
            float dtv = (e & 1) ? __high2float(dh2[e >> 1]) : __low2float(dh2[e >> 1]);
            float uv = reinterpret_cast<const float*>(&uq)[e];
            float bv = reinterpret_cast<const float*>(&bq)[e];
            float a = __expf(dtv * An);
            if (!PASS3) sdt += dtv;
            h = a * h + (dtv * uv) * bv;
            if (PASS3) {
                float cv = reinterpret_cast<const float*>(&cq)[e];
                float yv = red16(h * cv);
                const int i15 = (qi & 3) * 4 + j;
                if (i15 == n) ystash = yv;
                if (i15 == 15) {
                    int tb = t0 + (qi >> 2) * 16 + n;
                    int aw = REV ? (Lc - 1 - tb) : tb;
                    yrow[aw] = __float2half(ystash);     // 16-lane coalesced
                }
            }
        }
    }

    if (!PASS3) {
        P[pidx] = __expf(An * sdt);
        S[pidx] = h;
    }
}

template<int PASS3>
__global__ __launch_bounds__(256) void kscan(const __half* __restrict__ dtH,
                                             const float* __restrict__ xc,
                                             const float* __restrict__ uT,
                                             const float* __restrict__ BsT,
                                             const float* __restrict__ CsT,
                                             const float* __restrict__ alogf,
                                             float* __restrict__ P,
                                             float* __restrict__ S,
                                             __half* __restrict__ ysH)
{
    __shared__ float uL[16 * 132];
    __shared__ float bL[16 * 132];
    __shared__ float cL[PASS3 ? 16 * 132 : 4];
    __shared__ __half dL[16 * 136];

    int c  = blockIdx.x & 31;
    int t1 = blockIdx.x >> 5;          // 0..95
    int dg = t1 % 12;
    int kk = (t1 / 12) & 3;
    int b  = t1 / 48;
    int n  = threadIdx.x & 15, dl = threadIdx.x >> 4;
    int d  = dg * 16 + dl;

    const float* ubz = ((kk & 1) ? uT : xc) + (size_t)b * Dd * Lc;
    const float*  ubase = ubz + (size_t)d * Lc;
    const __half* dbase = dtH + ((size_t)((b * Kk + kk) * Dd + d)) * Lc;
    const float*  Bbase = BsT + ((size_t)((b * Kk + kk) * 16 + dl)) * Lc;
    const float*  Cbase = CsT + ((size_t)((b * Kk + kk) * 16 + dl)) * Lc;

    float An  = -__expf(alogf[(kk * Dd + d) * 16 + n]);
    size_t pidx = (((size_t)(b * Kk + kk) * Dd + d) * NC + c) * 16 + n;
    __half* yrow = PASS3 ? ysH + ((size_t)(kk * Bsz + b) * Dd + d) * Lc : nullptr;

    if (kk >= 2)
        scan_run<1, PASS3>(ubase, dbase, Bbase, Cbase, uL, bL, cL, dL,
                           dl, n, c, An, P, S, pidx, yrow);
    else
        scan_run<0, PASS3>(ubase, dbase, Bbase, Cbase, uL, bL, cL, dL,
                           dl, n, c, An, P, S, pidx, yrow);
}

// ---------------- K6: chunk-level scan; carry-in written in place over P ----------------
__global__ __launch_bounds__(64) void k6_pass2(float* __restrict__ P, const float* __restrict__ S)
{
    int g = blockIdx.x * 64 + threadIdx.x;   // 24576 (384 blocks x 64)
    int n = g & 15;
    int chain = g >> 4;
    size_t base = (size_t)chain * NC * 16 + n;
    float h = 0.f;
#pragma unroll
    for (int c = 0; c < NC; ++c) {
        size_t id = base + (size_t)c * 16;
        float p = P[id], s = S[id];
        P[id] = h;
        h = p * h + s;
    }
}

// ---------------- K8t: ysT = transpose(ys1 + ys3) per (b,d) ----------------
__global__ __launch_bounds__(256) void k8t(const __half* __restrict__ ysH,
                                           __half* __restrict__ ysT)
{
    __shared__ float t[64 * 65];
    int bid = blockIdx.x;
    int d = bid % Dd, b = bid / Dd;
    const __half* y1 = ysH + ((size_t)(1 * Bsz + b) * Dd + d) * Lc;
    const __half* y3 = ysH + ((size_t)(3 * Bsz + b) * Dd + d) * Lc;
    __half* dst = ysT + ((size_t)b * Dd + d) * Lc;
    for (int e = threadIdx.x; e < 4096; e += 256)
        t[(e >> 6) * 65 + (e & 63)] = __half2float(y1[e]) + __half2float(y3[e]);
    __syncthreads();
    for (int e = threadIdx.x; e < 4096; e += 256)
        dst[e] = __float2half(t[(e & 63) * 65 + (e >> 6)]);
}

// ------- K8: merge + Ds-fold + LayerNorm + SiLU(z) gate -> gH (B,L,Di) f16 -------
__global__ __launch_bounds__(256) void k8_norm(const __half* __restrict__ ysH,
                                               const __half* __restrict__ ysT,
                                               const __half* __restrict__ zT,
                                               const float* __restrict__ xc,
                                               const float* __restrict__ dsf,
                                               const float* __restrict__ nwf,
                                               const float* __restrict__ nbf,
                                               __half* __restrict__ gH)
{
    __shared__ float yt[192 * 33];
    __shared__ float ps1[8 * 32], ps2[8 * 32];
    __shared__ float mu[32], rs[32];
    int bid = blockIdx.x;
    int pt = bid & 127, b = bid >> 7;
    int p0 = pt * 32;
    for (int e = threadIdx.x; e < 192 * 32; e += 256) {
        int d = e >> 5, p = e & 31;
        size_t r0 = ((size_t)(0 * Bsz + b) * Dd + d) * Lc + p0 + p;
        size_t r2 = ((size_t)(2 * Bsz + b) * Dd + d) * Lc + p0 + p;
        size_t rt = ((size_t)b * Dd + d) * Lc + p0 + p;
        float ds4 = dsf[d] + dsf[192 + d] + dsf[384 + d] + dsf[576 + d];
        yt[d * 33 + p] = __half2float(ysH[r0]) + __half2float(ysH[r2])
                       + __half2float(ysT[rt])
                       + xc[((size_t)b * Dd + d) * Lc + p0 + p] * ds4;
    }
    __syncthreads();
    {
        int p = threadIdx.x & 31, q = threadIdx.x >> 5;
        float s1 = 0.f, s2 = 0.f;
        for (int dd = 0; dd < 24; ++dd) {
            float v = yt[(q * 24 + dd) * 33 + p];
            s1 += v; s2 += v * v;
        }
        ps1[q * 32 + p] = s1; ps2[q * 32 + p] = s2;
    }
    __syncthreads();
    if (threadIdx.x < 32) {
        int p = threadIdx.x;
        float s1 = 0.f, s2 = 0.f;
        for (int q = 0; q < 8; ++q) { s1 += ps1[q * 32 + p]; s2 += ps2[q * 32 + p]; }
        float m = s1 * (1.f / 192.f);
        float var = s2 * (1.f / 192.f) - m * m;
        mu[p] = m; rs[p] = rsqrtf(var + 1e-5f);
    }
    __syncthreads();
    for (int e = threadIdx.x; e < 192 * 32; e += 256) {
        int d = e >> 5, p = e & 31;
        float v = (yt[d * 33 + p] - mu[p]) * rs[p] * nwf[d] + nbf[d];
        float zv = __half2float(zT[((size_t)b * Dd + d) * Lc + p0 + p]);
        yt[d * 33 + p] = v * zv;
    }
    __syncthreads();
    for (int i = threadIdx.x; i < 32 * 192; i += 256) {
        int p = i / 192, d = i - p * 192;
        gH[((size_t)b * Lc + p0 + p) * Dd + d] = __float2half(yt[d * 33 + p]);
    }
}

// ---------------- K10: out_proj GEMM (8192 x 96 x 192) ----------------
__global__ __launch_bounds__(256) void k10_outproj(const __half* __restrict__ gH,
                                                   const float* __restrict__ wof,
                                                   const int* __restrict__ flag,
                                                   void* __restrict__ outv)
{
    __shared__ float wT[192 * 100];   // [d][c], padded
    const int bf = flag[0];
    for (int e = threadIdx.x; e < 96 * 192; e += 256) {
        int cI = e / 192, dI = e - cI * 192;
        wT[dI * 100 + cI] = wof[e];
    }
    __syncthreads();
    int r0 = blockIdx.x * 32;
    int r = threadIdx.x >> 3, cg = threadIdx.x & 7;
    const __half* grow = gH + (size_t)(r0 + r) * Dd;
    float acc[12];
#pragma unroll
    for (int i = 0; i < 12; ++i) acc[i] = 0.f;
    for (int d0 = 0; d0 < 192; d0 += 8) {
        __half2 g2[4];
        *reinterpret_cast<uint4*>(g2) = *reinterpret_cast<const uint4*>(grow + d0);
#pragma unroll
        for (int j = 0; j < 8; ++j) {
            float gf = (j & 1) ? __high2float(g2[j >> 1]) : __low2float(g2[j >> 1]);
            const float* wrow = &wT[(d0 + j) * 100 + cg * 12];
            float4 w0 = *reinterpret_cast<const float4*>(wrow);
            float4 w1 = *reinterpret_cast<const float4*>(wrow + 4);
            float4 w2 = *reinterpret_cast<const float4*>(wrow + 8);
            acc[0] += gf * w0.x; acc[1] += gf * w0.y; acc[2]  += gf * w0.z; acc[3]  += gf * w0.w;
            acc[4] += gf * w1.x; acc[5] += gf * w1.y; acc[6]  += gf * w1.z; acc[7]  += gf * w1.w;
            acc[8] += gf * w2.x; acc[9] += gf * w2.y; acc[10] += gf * w2.z; acc[11] += gf * w2.w;
        }
    }
    size_t obase = (size_t)(r0 + r) * Cc + cg * 12;
    if (bf) {
        unsigned short* o = (unsigned short*)outv;
#pragma unroll
        for (int cc = 0; cc < 12; ++cc) o[obase + cc] = f2b(acc[cc]);
    } else {
        float* o = (float*)outv;
#pragma unroll
        for (int cc = 0; cc < 12; ++cc) o[obase + cc] = acc[cc];
    }
}

extern "C" void kernel_launch(void* const* d_in, const int* in_sizes, int n_in,
                              void* d_out, int out_size, void* d_ws, size_t ws_size,
                              hipStream_t stream)
{
    (void)out_size; (void)ws_size;
    float* ws = (float*)d_ws;
    int* flag = (int*)ws;

    // converted weight region (inputs 1..11), starts at 64, ends < 131072
    int off[12]; int tot = 64;
    off[0] = 0;
    for (int i = 1; i < 12; ++i) {
        off[i] = tot;
        int n = (i < n_in) ? in_sizes[i] : 0;
        tot += (n + 63) & ~63;
    }
    float* winf = ws + off[1];
    float* cwf  = ws + off[2];
    float* cbf  = ws + off[3];
    float* dtwf = ws + off[5];
    float* dtbf = ws + off[6];
    float* alogf= ws + off[7];
    float* dsf  = ws + off[8];
    float* nwf  = ws + off[9];
    float* nbf  = ws + off[10];
    float* wof  = ws + off[11];

    const size_t BASE = 131072;
    __half* dtH = (__half*)(ws + BASE);            // 6291456 h  (B,K,Di,L)
    float*  xc  = ws + BASE + 3145728;             // 1572864 f  (B,Di,L)
    float*  uT  = ws + BASE + 4718592;             // 1572864 f  (B,Di,L) col-major
    float*  BsT = ws + BASE + 6291456;             // 524288 f   (B,K,N,L)
    float*  CsT = ws + BASE + 6815744;             // 524288 f
    float*  P   = ws + BASE + 7340032;             // 786432 f   ; alias ysT after pass3
    float*  S   = ws + BASE + 8126464;             // 786432 f   ; alias gH after k6
    __half* zT  = (__half*)(ws + BASE + 8912896);  // 1572864 h  (B,Di,L)
    float*  xiT = ws + BASE + 9699328;             // 1572864 f  (B,Di,L); dead after k2b
    __half* ysH = (__half*)(ws + BASE + 9699328);  // 6291456 h  (K,B,Di,L) — overlays xiT
    __half* ysT = (__half*)P;                      // 1572864 h  (B,Di,L)
    __half* gH  = (__half*)S;                      // 1572864 h  (B,L,Di)
    float*  Wg  = ws + BASE + 12845056;            // 30720 f    (K,Di,40) padded W
    // end = BASE + 12875776 floats = 52.1 MB

    Cv cv;
    for (int i = 0; i < 11; ++i) {
        int t = i + 1;
        cv.src[i] = (t < n_in) ? d_in[t] : d_in[0];
        cv.off[i] = off[t];
        cv.n[i]   = (t < n_in) ? in_sizes[t] : 0;
    }
    // move slots: src[0..10] correspond to inputs 1..11; slot 11 = Wg build (raw xpw)
    Cv cv2;
    for (int i = 0; i < 11; ++i) { cv2.src[i] = cv.src[i]; cv2.off[i] = cv.off[i]; cv2.n[i] = cv.n[i]; }
    cv2.src[11] = (4 < n_in) ? d_in[4] : d_in[0];
    cv2.off[11] = (int)(BASE + 12845056);
    cv2.n[11]   = 4 * 192 * 40;

    k0_detect   <<<dim3(1),    dim3(256), 0, stream>>>((const unsigned short*)d_in[0], flag);
    k0b_convert <<<dim3(144, 12), dim3(256), 0, stream>>>(cv2, flag, ws);
    k1_inproj   <<<dim3(512),  dim3(256), 0, stream>>>(d_in[0], flag, winf, xiT, zT);
    k2b_conv    <<<dim3(768),  dim3(256), 0, stream>>>(xiT, cwf, cbf, xc, uT);
    k3_proj     <<<dim3(512),  dim3(256), 0, stream>>>(xc, uT, Wg, dtwf, dtbf, dtH, BsT, CsT);
    kscan<0>    <<<dim3(3072), dim3(256), 0, stream>>>(dtH, xc, uT, BsT, CsT, alogf, P, S, ysH);
    k6_pass2    <<<dim3(384),  dim3(64),  0, stream>>>(P, S);
    kscan<1>    <<<dim3(3072), dim3(256), 0, stream>>>(dtH, xc, uT, BsT, CsT, alogf, P, S, ysH);
    k8t         <<<dim3(384),  dim3(256), 0, stream>>>(ysH, ysT);
    k8_norm     <<<dim3(256),  dim3(256), 0, stream>>>(ysH, ysT, zT, xc, dsf, nwf, nbf, gH);
    k10_outproj <<<dim3(256),  dim3(256), 0, stream>>>(gH, wof, flag, d_out);
}

// Round 11
// 179.562 us; speedup vs baseline: 2.2973x; 1.0962x over previous
//
#include <hip/hip_runtime.h>
#include <hip/hip_fp16.h>
#include <math.h>

// SS2D fused block. B=2, H=W=64, L=4096, C=96, Di=192, K=4, N=16, R=6.
// Input dtype (bf16 vs f32) detected at runtime; internal compute f32 (dt/z/ys f16).
// Workspace: ~52.1 MB.

static constexpr int Bsz = 2;
static constexpr int Lc  = 4096;
static constexpr int Cc  = 96;
static constexpr int Dd  = 192;
static constexpr int Kk  = 4;
static constexpr int NC  = 32;     // chunks of 128 steps

__device__ __forceinline__ float bu(unsigned short v) {
    return __uint_as_float((unsigned int)v << 16);
}
__device__ __forceinline__ unsigned short f2b(float f) {
    unsigned int u = __float_as_uint(f);
    return (unsigned short)((u + 0x7fffu + ((u >> 16) & 1u)) >> 16);
}

// DPP 16-lane row reduction: 4 full-rate VALU adds, no DS pipe.
template<int CTRL>
__device__ __forceinline__ float dppadd(float x) {
    return x + __int_as_float(__builtin_amdgcn_update_dpp(
        0, __float_as_int(x), CTRL, 0xf, 0xf, true));
}
__device__ __forceinline__ float red16(float x) {
    x = dppadd<0xB1>(x);    // quad_perm [1,0,3,2]  (xor 1)
    x = dppadd<0x4E>(x);    // quad_perm [2,3,0,1]  (xor 2)
    x = dppadd<0x124>(x);   // row_ror:4
    x = dppadd<0x128>(x);   // row_ror:8
    return x;
}

// ---------------- K0: dtype detector (bf16 vs f32) ----------------
__global__ __launch_bounds__(256) void k0_detect(const unsigned short* __restrict__ x,
                                                 int* __restrict__ flag)
{
    __shared__ int s[256];
    int cnt = 0;
    for (int i = threadIdx.x; i < 4096; i += 256) {
        int e = (x[i] >> 7) & 0xFF;
        cnt += (e >= 118 && e <= 131) ? 1 : 0;
    }
    s[threadIdx.x] = cnt;
    __syncthreads();
    for (int st = 128; st > 0; st >>= 1) {
        if (threadIdx.x < st) s[threadIdx.x] += s[threadIdx.x + st];
        __syncthreads();
    }
    if (threadIdx.x == 0) flag[0] = (s[0] >= 3072) ? 1 : 0;
}

// ------- K0b: convert weight inputs (1..11) to f32; slot 11 builds Wg -------
struct Cv {
    const void* src[12];
    int off[12];
    int n[12];
};
__global__ __launch_bounds__(256) void k0b_convert(Cv cv, const int* __restrict__ flag,
                                                   float* __restrict__ dstbase)
{
    int bf = flag[0];
    int t = blockIdx.y;
    int i = blockIdx.x * 256 + threadIdx.x;
    if (i >= cv.n[t]) return;
    if (t == 11) {
        // Wg[k][d][40] = x_proj_weight[k][cp][d] (cp>=38 -> 0), from RAW input
        int cp = i % 40;
        int d  = (i / 40) % 192;
        int k  = i / 7680;
        float v = 0.f;
        if (cp < 38) {
            size_t si = (size_t)(k * 38 + cp) * 192 + d;
            v = bf ? bu(((const unsigned short*)cv.src[11])[si])
                   : ((const float*)cv.src[11])[si];
        }
        dstbase[cv.off[11] + i] = v;
        return;
    }
    float v;
    if (bf) v = bu(((const unsigned short*)cv.src[t])[i]);
    else    v = ((const float*)cv.src[t])[i];
    dstbase[cv.off[t] + i] = v;
}

// -------- K1: in_proj GEMM (8192x384x96) -> xiT (B,Di,L) f32, zT (B,Di,L) f16 --------
// Block = 64 rows x 4 wave-uniform j-groups (24 j each). W via scalar loads.
__global__ __launch_bounds__(256) void k1_inproj(const void* __restrict__ xraw,
                                                 const int* __restrict__ flag,
                                                 const float* __restrict__ wf,
                                                 float* __restrict__ xiT, __half* __restrict__ zT)
{
    __shared__ float xT[64 * 97];
    const int bf = flag[0];
    int lt = blockIdx.x & 127;          // 128 tiles of 64 rows over B*L
    int jq = blockIdx.x >> 7;           // 0..3
    int row0 = lt * 64;
    for (int e = threadIdx.x; e < 64 * 96; e += 256) {
        int i = e / 96, c = e % 96;
        size_t idx = (size_t)(row0 + i) * Cc + c;
        xT[i * 97 + c] = bf ? bu(((const unsigned short*)xraw)[idx])
                            : ((const float*)xraw)[idx];
    }
    __syncthreads();
    int pi = threadIdx.x & 63;
    int q  = __builtin_amdgcn_readfirstlane(threadIdx.x >> 6);
    int j0 = jq * 96 + q * 24;
    float acc[24];
#pragma unroll
    for (int j = 0; j < 24; ++j) acc[j] = 0.f;
    for (int c4 = 0; c4 < 24; ++c4) {
        float xv0 = xT[pi * 97 + c4 * 4 + 0];
        float xv1 = xT[pi * 97 + c4 * 4 + 1];
        float xv2 = xT[pi * 97 + c4 * 4 + 2];
        float xv3 = xT[pi * 97 + c4 * 4 + 3];
#pragma unroll
        for (int j = 0; j < 24; ++j) {
            float4 w4 = *reinterpret_cast<const float4*>(&wf[(size_t)(j0 + j) * 96 + c4 * 4]);
            acc[j] += w4.x * xv0 + w4.y * xv1 + w4.z * xv2 + w4.w * xv3;
        }
    }
    int b = row0 >> 12;
    int l = (row0 & 4095) + pi;
    if (jq < 2) {
#pragma unroll
        for (int j = 0; j < 24; ++j)
            xiT[((size_t)b * Dd + j0 + j) * Lc + l] = acc[j];
    } else {
#pragma unroll
        for (int j = 0; j < 24; ++j) {
            float v = acc[j];
            zT[((size_t)b * Dd + (j0 + j - 192)) * Lc + l] =
                __float2half(v / (1.f + __expf(-v)));
        }
    }
}

// -------- K2b: depthwise 3x3 conv + bias + SiLU (channel-first), writes xc and uT --------
__global__ __launch_bounds__(256) void k2b_conv(const float* __restrict__ xiT,
                                                const float* __restrict__ cwf,
                                                const float* __restrict__ cbf,
                                                float* __restrict__ xc,
                                                float* __restrict__ uT)
{
    __shared__ float inl[34 * 66];   // rows h0-1..h0+32, cols zero-padded
    __shared__ float outl[32 * 65];
    int bid = blockIdx.x;
    int half = bid & 1;
    int d = (bid >> 1) % Dd;
    int b = bid / (2 * Dd);
    int h0 = half * 32;
    const float* src = xiT + (size_t)(b * Dd + d) * Lc;
    for (int r = threadIdx.x; r < 34; r += 256) {
        inl[r * 66 + 0] = 0.f;
        inl[r * 66 + 65] = 0.f;
    }
    for (int e = threadIdx.x; e < 34 * 64; e += 256) {
        int row = e >> 6, w = e & 63;
        int h = h0 - 1 + row;
        inl[row * 66 + 1 + w] = (h >= 0 && h < 64) ? src[h * 64 + w] : 0.f;
    }
    __syncthreads();
    float wgt[9];
#pragma unroll
    for (int t = 0; t < 9; t++) wgt[t] = cwf[d * 9 + t];
    float bias = cbf[d];
    int hs = threadIdx.x >> 6, w = threadIdx.x & 63;
    float* dstrow = xc + (size_t)(b * Dd + d) * Lc;
#pragma unroll
    for (int it = 0; it < 8; ++it) {
        int hh = it * 4 + hs;
        float acc = bias;
#pragma unroll
        for (int dy = 0; dy < 3; ++dy) {
            const float* rp = &inl[(hh + dy) * 66 + w];
#pragma unroll
            for (int dx = 0; dx < 3; ++dx)
                acc += rp[dx] * wgt[dy * 3 + dx];
        }
        float s = acc / (1.f + __expf(-acc));
        dstrow[(h0 + hh) * 64 + w] = s;
        outl[hh * 65 + w] = s;
    }
    __syncthreads();
    float* udst = uT + (size_t)(b * Dd + d) * Lc;
    for (int e = threadIdx.x; e < 2048; e += 256) {
        int w2 = e >> 5, hh2 = e & 31;
        udst[w2 * 64 + h0 + hh2] = outl[hh2 * 65 + w2];
    }
}

// -------- K3: per-direction projection + dt-proj + softplus --------
// x-tile (192 d x 64 pos) staged in LDS once (burst loads); K-loop reads LDS.
__global__ __launch_bounds__(256) void k3_proj(const float* __restrict__ xc,
                                               const float* __restrict__ uT,
                                               const float* __restrict__ Wg,
                                               const float* __restrict__ dtwf,
                                               const float* __restrict__ dtbf,
                                               __half* __restrict__ dtH,
                                               float* __restrict__ BsT, float* __restrict__ CsT)
{
    __shared__ float xL[192 * 64];      // 48 KB
    __shared__ float rawdt[6][64];
    int bid = blockIdx.x;            // 512 = 64 tiles x 4 k x 2 b
    int pt = bid & 63, k = (bid >> 6) & 3, b = bid >> 8;
    int s0 = pt * 64;
    const float* xb = ((k & 1) ? uT : xc) + (size_t)b * Dd * Lc + s0;
    // stage 192 rows x 64 cols, fully coalesced float4 bursts (12 per thread)
    for (int e = threadIdx.x; e < 3072; e += 256) {
        int d = e >> 4, c4 = e & 15;
        *reinterpret_cast<float4*>(&xL[d * 64 + c4 * 4]) =
            *reinterpret_cast<const float4*>(xb + (size_t)d * Lc + c4 * 4);
    }
    __syncthreads();

    int pi = threadIdx.x & 63;
    int q  = __builtin_amdgcn_readfirstlane(threadIdx.x >> 6);   // wave-uniform

    const float* wk = Wg + (size_t)k * 192 * 40 + q * 10;

    float acc[10];
#pragma unroll
    for (int j = 0; j < 10; ++j) acc[j] = 0.f;

    for (int d = 0; d < 192; ++d) {
        float xv = xL[d * 64 + pi];             // LDS, 2-way alias = free
        const float* wrow = wk + d * 40;        // uniform -> s_load
#pragma unroll
        for (int j = 0; j < 10; ++j) acc[j] += wrow[j] * xv;
    }

    if (q == 0) {
#pragma unroll
        for (int j = 0; j < 6; ++j) rawdt[j][pi] = acc[j];
    }
    size_t bk16 = (size_t)(b * Kk + k) * 16;
#pragma unroll
    for (int j = 0; j < 10; ++j) {
        int cp = q * 10 + j;
        if (cp >= 6 && cp < 22)
            BsT[(bk16 + (cp - 6)) * Lc + s0 + pi] = acc[j];
        else if (cp >= 22 && cp < 38)
            CsT[(bk16 + (cp - 22)) * Lc + s0 + pi] = acc[j];
    }
    __syncthreads();

    float raws[6];
#pragma unroll
    for (int r = 0; r < 6; ++r) raws[r] = rawdt[r][pi];
    const float* dtw = dtwf + (size_t)(k * 192 + q * 48) * 6;    // uniform
    const float* dtb = dtbf + k * 192 + q * 48;                  // uniform
    __half* dto = dtH + ((size_t)(b * Kk + k) * Dd + q * 48) * Lc + s0 + pi;
    for (int dd = 0; dd < 48; ++dd) {
        float s = dtb[dd];
#pragma unroll
        for (int r = 0; r < 6; ++r) s += raws[r] * dtw[dd * 6 + r];
        // softplus: log(1+e^-|s|) has no cancellation (arg in (1,2]); abs err <1e-7
        float sp = fmaxf(s, 0.f) + __logf(1.f + __expf(-fabsf(s)));
        dto[(size_t)dd * Lc] = __float2half(sp);
    }
}

// ---------------- KSCAN: chunked selective scan, single LDS tile, 1 barrier ----------------
template<int REV, int PASS3>
__device__ __forceinline__ void scan_run(const float* __restrict__ ubase,
                                         const __half* __restrict__ dbase,
                                         const float* __restrict__ Bbase,
                                         const float* __restrict__ Cbase,
                                         float* uL, float* bL, float* cL, __half* dL,
                                         int dl, int n, int c,
                                         float An,
                                         float* __restrict__ P, float* __restrict__ S,
                                         size_t pidx, __half* __restrict__ yrow)
{
    const int t0 = c * 128;
    const int tg = REV ? (Lc - 128 - t0) : t0;

    // ---- stage 128 steps (transient registers, die before barrier) ----
    {
        float4 ru0 = *reinterpret_cast<const float4*>(ubase + tg + n * 4);
        float4 ru1 = *reinterpret_cast<const float4*>(ubase + tg + 64 + n * 4);
        float4 rb0 = *reinterpret_cast<const float4*>(Bbase + tg + n * 4);
        float4 rb1 = *reinterpret_cast<const float4*>(Bbase + tg + 64 + n * 4);
        uint4  rd  = *reinterpret_cast<const uint4*>(dbase + tg + n * 8);
        *reinterpret_cast<float4*>(uL + dl * 132 + n * 4) = ru0;
        *reinterpret_cast<float4*>(uL + dl * 132 + 64 + n * 4) = ru1;
        *reinterpret_cast<float4*>(bL + dl * 132 + n * 4) = rb0;
        *reinterpret_cast<float4*>(bL + dl * 132 + 64 + n * 4) = rb1;
        *reinterpret_cast<uint4*>(dL + dl * 136 + n * 8) = rd;
        if (PASS3) {
            float4 rc0 = *reinterpret_cast<const float4*>(Cbase + tg + n * 4);
            float4 rc1 = *reinterpret_cast<const float4*>(Cbase + tg + 64 + n * 4);
            *reinterpret_cast<float4*>(cL + dl * 132 + n * 4) = rc0;
            *reinterpret_cast<float4*>(cL + dl * 132 + 64 + n * 4) = rc1;
        }
    }
    __syncthreads();

    float h = PASS3 ? P[pidx] : 0.f;
    float sdt = 0.f, ystash = 0.f;

#pragma unroll 4
    for (int qi = 0; qi < 32; ++qi) {
        const int col4 = REV ? (124 - qi * 4) : (qi * 4);
        float4 uq = *reinterpret_cast<const float4*>(uL + dl * 132 + col4);
        float4 bq = *reinterpret_cast<const float4*>(bL + n * 132 + col4);
        float4 cq{};
        if (PASS3) cq = *reinterpret_cast<const float4*>(cL + n * 132 + col4);
        uint2 dq = *reinterpret_cast<const uint2*>(dL + dl * 136 + col4);
        const __half2* dh2 = reinterpret_cast<const __half2*>(&dq);
#pragma unroll
        for (int j = 0; j < 4; ++j) {
            const int e = REV ? (3 - j) : j;
            float dtv = (e & 1) ? __high2float(dh2[e >> 1]) : __low2float(dh2[e >> 1]);
            float uv = reinterpret_cast<const float*>(&uq)[e];
            float bv = reinterpret_cast<const float*>(&bq)[e];
            float a = __expf(dtv * An);
            if (!PASS3) sdt += dtv;
            h = a * h + (dtv * uv) * bv;
            if (PASS3) {
                float cv = reinterpret_cast<const float*>(&cq)[e];
                float yv = red16(h * cv);
                const int i15 = (qi & 3) * 4 + j;
                if (i15 == n) ystash = yv;
                if (i15 == 15) {
                    int tb = t0 + (qi >> 2) * 16 + n;
                    int aw = REV ? (Lc - 1 - tb) : tb;
                    yrow[aw] = __float2half(ystash);     // 16-lane coalesced
                }
            }
        }
    }

    if (!PASS3) {
        P[pidx] = __expf(An * sdt);
        S[pidx] = h;
    }
}

template<int PASS3>
__global__ __launch_bounds__(256) void kscan(const __half* __restrict__ dtH,
                                             const float* __restrict__ xc,
                                             const float* __restrict__ uT,
                                             const float* __restrict__ BsT,
                                             const float* __restrict__ CsT,
                                             const float* __restrict__ alogf,
                                             float* __restrict__ P,
                                             float* __restrict__ S,
                                             __half* __restrict__ ysH)
{
    __shared__ float uL[16 * 132];
    __shared__ float bL[16 * 132];
    __shared__ float cL[PASS3 ? 16 * 132 : 4];
    __shared__ __half dL[16 * 136];

    int c  = blockIdx.x & 31;
    int t1 = blockIdx.x >> 5;          // 0..95
    int dg = t1 % 12;
    int kk = (t1 / 12) & 3;
    int b  = t1 / 48;
    int n  = threadIdx.x & 15, dl = threadIdx.x >> 4;
    int d  = dg * 16 + dl;

    const float* ubz = ((kk & 1) ? uT : xc) + (size_t)b * Dd * Lc;
    const float*  ubase = ubz + (size_t)d * Lc;
    const __half* dbase = dtH + ((size_t)((b * Kk + kk) * Dd + d)) * Lc;
    const float*  Bbase = BsT + ((size_t)((b * Kk + kk) * 16 + dl)) * Lc;
    const float*  Cbase = CsT + ((size_t)((b * Kk + kk) * 16 + dl)) * Lc;

    float An  = -__expf(alogf[(kk * Dd + d) * 16 + n]);
    size_t pidx = (((size_t)(b * Kk + kk) * Dd + d) * NC + c) * 16 + n;
    __half* yrow = PASS3 ? ysH + ((size_t)(kk * Bsz + b) * Dd + d) * Lc : nullptr;

    if (kk >= 2)
        scan_run<1, PASS3>(ubase, dbase, Bbase, Cbase, uL, bL, cL, dL,
                           dl, n, c, An, P, S, pidx, yrow);
    else
        scan_run<0, PASS3>(ubase, dbase, Bbase, Cbase, uL, bL, cL, dL,
                           dl, n, c, An, P, S, pidx, yrow);
}

// ---------------- K6: chunk-level scan; carry-in written in place over P ----------------
__global__ __launch_bounds__(64) void k6_pass2(float* __restrict__ P, const float* __restrict__ S)
{
    int g = blockIdx.x * 64 + threadIdx.x;   // 24576 (384 blocks x 64)
    int n = g & 15;
    int chain = g >> 4;
    size_t base = (size_t)chain * NC * 16 + n;
    float h = 0.f;
#pragma unroll
    for (int c = 0; c < NC; ++c) {
        size_t id = base + (size_t)c * 16;
        float p = P[id], s = S[id];
        P[id] = h;
        h = p * h + s;
    }
}

// ---------------- K8t: ysT = transpose(ys1 + ys3) per (b,d) ----------------
__global__ __launch_bounds__(256) void k8t(const __half* __restrict__ ysH,
                                           __half* __restrict__ ysT)
{
    __shared__ float t[64 * 65];
    int bid = blockIdx.x;
    int d = bid % Dd, b = bid / Dd;
    const __half* y1 = ysH + ((size_t)(1 * Bsz + b) * Dd + d) * Lc;
    const __half* y3 = ysH + ((size_t)(3 * Bsz + b) * Dd + d) * Lc;
    __half* dst = ysT + ((size_t)b * Dd + d) * Lc;
    for (int e = threadIdx.x; e < 4096; e += 256)
        t[(e >> 6) * 65 + (e & 63)] = __half2float(y1[e]) + __half2float(y3[e]);
    __syncthreads();
    for (int e = threadIdx.x; e < 4096; e += 256)
        dst[e] = __float2half(t[(e & 63) * 65 + (e >> 6)]);
}

// ------- K8: merge + Ds-fold + LayerNorm + SiLU(z) gate -> gH (B,L,Di) f16 -------
__global__ __launch_bounds__(256) void k8_norm(const __half* __restrict__ ysH,
                                               const __half* __restrict__ ysT,
                                               const __half* __restrict__ zT,
                                               const float* __restrict__ xc,
                                               const float* __restrict__ dsf,
                                               const float* __restrict__ nwf,
                                               const float* __restrict__ nbf,
                                               __half* __restrict__ gH)
{
    __shared__ float yt[192 * 33];
    __shared__ float ps1[8 * 32], ps2[8 * 32];
    __shared__ float mu[32], rs[32];
    int bid = blockIdx.x;
    int pt = bid & 127, b = bid >> 7;
    int p0 = pt * 32;
    for (int e = threadIdx.x; e < 192 * 32; e += 256) {
        int d = e >> 5, p = e & 31;
        size_t r0 = ((size_t)(0 * Bsz + b) * Dd + d) * Lc + p0 + p;
        size_t r2 = ((size_t)(2 * Bsz + b) * Dd + d) * Lc + p0 + p;
        size_t rt = ((size_t)b * Dd + d) * Lc + p0 + p;
        float ds4 = dsf[d] + dsf[192 + d] + dsf[384 + d] + dsf[576 + d];
        yt[d * 33 + p] = __half2float(ysH[r0]) + __half2float(ysH[r2])
                       + __half2float(ysT[rt])
                       + xc[((size_t)b * Dd + d) * Lc + p0 + p] * ds4;
    }
    __syncthreads();
    {
        int p = threadIdx.x & 31, q = threadIdx.x >> 5;
        float s1 = 0.f, s2 = 0.f;
        for (int dd = 0; dd < 24; ++dd) {
            float v = yt[(q * 24 + dd) * 33 + p];
            s1 += v; s2 += v * v;
        }
        ps1[q * 32 + p] = s1; ps2[q * 32 + p] = s2;
    }
    __syncthreads();
    if (threadIdx.x < 32) {
        int p = threadIdx.x;
        float s1 = 0.f, s2 = 0.f;
        for (int q = 0; q < 8; ++q) { s1 += ps1[q * 32 + p]; s2 += ps2[q * 32 + p]; }
        float m = s1 * (1.f / 192.f);
        float var = s2 * (1.f / 192.f) - m * m;
        mu[p] = m; rs[p] = rsqrtf(var + 1e-5f);
    }
    __syncthreads();
    for (int e = threadIdx.x; e < 192 * 32; e += 256) {
        int d = e >> 5, p = e & 31;
        float v = (yt[d * 33 + p] - mu[p]) * rs[p] * nwf[d] + nbf[d];
        float zv = __half2float(zT[((size_t)b * Dd + d) * Lc + p0 + p]);
        yt[d * 33 + p] = v * zv;
    }
    __syncthreads();
    for (int i = threadIdx.x; i < 32 * 192; i += 256) {
        int p = i / 192, d = i - p * 192;
        gH[((size_t)b * Lc + p0 + p) * Dd + d] = __float2half(yt[d * 33 + p]);
    }
}

// ---------------- K10: out_proj GEMM (8192 x 96 x 192) ----------------
__global__ __launch_bounds__(256) void k10_outproj(const __half* __restrict__ gH,
                                                   const float* __restrict__ wof,
                                                   const int* __restrict__ flag,
                                                   void* __restrict__ outv)
{
    __shared__ float wT[192 * 100];   // [d][c], padded
    const int bf = flag[0];
    for (int e = threadIdx.x; e < 96 * 192; e += 256) {
        int cI = e / 192, dI = e - cI * 192;
        wT[dI * 100 + cI] = wof[e];
    }
    __syncthreads();
    int r0 = blockIdx.x * 32;
    int r = threadIdx.x >> 3, cg = threadIdx.x & 7;
    const __half* grow = gH + (size_t)(r0 + r) * Dd;
    float acc[12];
#pragma unroll
    for (int i = 0; i < 12; ++i) acc[i] = 0.f;
    for (int d0 = 0; d0 < 192; d0 += 8) {
        __half2 g2[4];
        *reinterpret_cast<uint4*>(g2) = *reinterpret_cast<const uint4*>(grow + d0);
#pragma unroll
        for (int j = 0; j < 8; ++j) {
            float gf = (j & 1) ? __high2float(g2[j >> 1]) : __low2float(g2[j >> 1]);
            const float* wrow = &wT[(d0 + j) * 100 + cg * 12];
            float4 w0 = *reinterpret_cast<const float4*>(wrow);
            float4 w1 = *reinterpret_cast<const float4*>(wrow + 4);
            float4 w2 = *reinterpret_cast<const float4*>(wrow + 8);
            acc[0] += gf * w0.x; acc[1] += gf * w0.y; acc[2]  += gf * w0.z; acc[3]  += gf * w0.w;
            acc[4] += gf * w1.x; acc[5] += gf * w1.y; acc[6]  += gf * w1.z; acc[7]  += gf * w1.w;
            acc[8] += gf * w2.x; acc[9] += gf * w2.y; acc[10] += gf * w2.z; acc[11] += gf * w2.w;
        }
    }
    size_t obase = (size_t)(r0 + r) * Cc + cg * 12;
    if (bf) {
        unsigned short* o = (unsigned short*)outv;
#pragma unroll
        for (int cc = 0; cc < 12; ++cc) o[obase + cc] = f2b(acc[cc]);
    } else {
        float* o = (float*)outv;
#pragma unroll
        for (int cc = 0; cc < 12; ++cc) o[obase + cc] = acc[cc];
    }
}

extern "C" void kernel_launch(void* const* d_in, const int* in_sizes, int n_in,
                              void* d_out, int out_size, void* d_ws, size_t ws_size,
                              hipStream_t stream)
{
    (void)out_size; (void)ws_size;
    float* ws = (float*)d_ws;
    int* flag = (int*)ws;

    // converted weight region (inputs 1..11), starts at 64, ends < 131072
    int off[12]; int tot = 64;
    off[0] = 0;
    for (int i = 1; i < 12; ++i) {
        off[i] = tot;
        int n = (i < n_in) ? in_sizes[i] : 0;
        tot += (n + 63) & ~63;
    }
    float* winf = ws + off[1];
    float* cwf  = ws + off[2];
    float* cbf  = ws + off[3];
    float* dtwf = ws + off[5];
    float* dtbf = ws + off[6];
    float* alogf= ws + off[7];
    float* dsf  = ws + off[8];
    float* nwf  = ws + off[9];
    float* nbf  = ws + off[10];
    float* wof  = ws + off[11];

    const size_t BASE = 131072;
    __half* dtH = (__half*)(ws + BASE);            // 6291456 h  (B,K,Di,L)
    float*  xc  = ws + BASE + 3145728;             // 1572864 f  (B,Di,L)
    float*  uT  = ws + BASE + 4718592;             // 1572864 f  (B,Di,L) col-major
    float*  BsT = ws + BASE + 6291456;             // 524288 f   (B,K,N,L)
    float*  CsT = ws + BASE + 6815744;             // 524288 f
    float*  P   = ws + BASE + 7340032;             // 786432 f   ; alias ysT after pass3
    float*  S   = ws + BASE + 8126464;             // 786432 f   ; alias gH after k6
    __half* zT  = (__half*)(ws + BASE + 8912896);  // 1572864 h  (B,Di,L)
    float*  xiT = ws + BASE + 9699328;             // 1572864 f  (B,Di,L); dead after k2b
    __half* ysH = (__half*)(ws + BASE + 9699328);  // 6291456 h  (K,B,Di,L) — overlays xiT
    __half* ysT = (__half*)P;                      // 1572864 h  (B,Di,L)
    __half* gH  = (__half*)S;                      // 1572864 h  (B,L,Di)
    float*  Wg  = ws + BASE + 12845056;            // 30720 f    (K,Di,40) padded W
    // end = BASE + 12875776 floats = 52.1 MB

    Cv cv2;
    for (int i = 0; i < 11; ++i) {
        int t = i + 1;
        cv2.src[i] = (t < n_in) ? d_in[t] : d_in[0];
        cv2.off[i] = off[t];
        cv2.n[i]   = (t < n_in) ? in_sizes[t] : 0;
    }
    cv2.src[11] = (4 < n_in) ? d_in[4] : d_in[0];
    cv2.off[11] = (int)(BASE + 12845056);
    cv2.n[11]   = 4 * 192 * 40;

    k0_detect   <<<dim3(1),    dim3(256), 0, stream>>>((const unsigned short*)d_in[0], flag);
    k0b_convert <<<dim3(144, 12), dim3(256), 0, stream>>>(cv2, flag, ws);
    k1_inproj   <<<dim3(512),  dim3(256), 0, stream>>>(d_in[0], flag, winf, xiT, zT);
    k2b_conv    <<<dim3(768),  dim3(256), 0, stream>>>(xiT, cwf, cbf, xc, uT);
    k3_proj     <<<dim3(512),  dim3(256), 0, stream>>>(xc, uT, Wg, dtwf, dtbf, dtH, BsT, CsT);
    kscan<0>    <<<dim3(3072), dim3(256), 0, stream>>>(dtH, xc, uT, BsT, CsT, alogf, P, S, ysH);
    k6_pass2    <<<dim3(384),  dim3(64),  0, stream>>>(P, S);
    kscan<1>    <<<dim3(3072), dim3(256), 0, stream>>>(dtH, xc, uT, BsT, CsT, alogf, P, S, ysH);
    k8t         <<<dim3(384),  dim3(256), 0, stream>>>(ysH, ysT);
    k8_norm     <<<dim3(256),  dim3(256), 0, stream>>>(ysH, ysT, zT, xc, dsf, nwf, nbf, gH);
    k10_outproj <<<dim3(256),  dim3(256), 0, stream>>>(gH, wof, flag, d_out);
}